// Round 5
// baseline (784.081 us; speedup 1.0000x reference)
//
#include <hip/hip_runtime.h>

typedef unsigned short u16;
typedef __attribute__((ext_vector_type(8))) short bf16x8;
typedef __attribute__((ext_vector_type(4))) float f32x4;

#define INV_SCALE 0.17677669529663687f

static __device__ __forceinline__ float b2f(u16 u) {
    union { unsigned int i; float f; } v; v.i = ((unsigned int)u) << 16; return v.f;
}
static __device__ __forceinline__ u16 f2b(float f) {
    union { float f; unsigned int i; } v; v.f = f;
    unsigned int r = (v.i + 0x7FFFu + ((v.i >> 16) & 1u)) >> 16;
    return (u16)r;
}

// ---- param arena segment table (bf16 elements), shared host/device ----
#define NSEG 23
__device__ __constant__ int d_seg_off[NSEG + 1] = {
    0, 8192, 270336, 272384, 272512, 273536, 273664, 273792, 322944, 372096,
    421248, 470400, 519552, 519936, 520320, 520704, 717312, 718848, 915456,
    915840, 916224, 916608, 916736, 916744};
static const int h_seg_off[NSEG + 1] = {
    0, 8192, 270336, 272384, 272512, 273536, 273664, 273792, 322944, 372096,
    421248, 470400, 519552, 519936, 520320, 520704, 717312, 718848, 915456,
    915840, 916224, 916608, 916736, 916744};
#define ARENA_TOTAL 916744

struct ParamPtrs { const void* p[NSEG]; };

// ---------------------------------------------------------------- param convert
__global__ __launch_bounds__(256) void convert_params(ParamPtrs pp, u16* __restrict__ arena) {
    const unsigned int probe = ((const unsigned int*)pp.p[13])[0];   // ln1_g[0] == 1.0
    const bool f32 = (probe == 0x3F800000u);
    for (int e = blockIdx.x * 256 + threadIdx.x; e < ARENA_TOTAL; e += gridDim.x * 256) {
        int k = 0;
        #pragma unroll
        for (int s2 = 1; s2 < NSEG; ++s2) if (e >= d_seg_off[s2]) k = s2;
        int local = e - d_seg_off[k];
        u16 v;
        if (k == 22 && local >= 1) v = 0;   // bout padded 1 -> 8
        else v = f32 ? f2b(((const float*)pp.p[k])[local]) : ((const u16*)pp.p[k])[local];
        arena[e] = v;
    }
}

// ---------------------------------------------------------------- mask dtype probe (tiny)
__global__ __launch_bounds__(256) void probe_kernel(const void* mask, int* __restrict__ mode) {
    __shared__ int f16, f32s, u8s;
    int tid = threadIdx.x;
    if (tid == 0) { f16 = 0; f32s = 0; u8s = 0; }
    __syncthreads();
    const u16* mu = (const u16*)mask;
    const unsigned int* mw = (const unsigned int*)mask;
    if (mu[2 * tid] == 0x3F80u) atomicOr(&f16, 1);
    if (mw[tid] == 0x3F800000u) atomicOr(&f32s, 1);
    if (mw[tid] > 1u) atomicOr(&u8s, 1);
    __syncthreads();
    if (tid == 0) mode[0] = f16 ? 0 : (f32s ? 3 : (u8s ? 1 : 2));
}

// ---------------------------------------------------------------- tok assembly (mask fused)
__global__ __launch_bounds__(256) void assemble_kernel(
    const u16* __restrict__ x, const u16* __restrict__ ea,
    const void* __restrict__ mask, const int* __restrict__ modeptr,
    const u16* __restrict__ nodeW, const u16* __restrict__ nodeB,
    const u16* __restrict__ edgeW, const u16* __restrict__ edgeB, const u16* __restrict__ noedge,
    float* __restrict__ tokf, u16* __restrict__ tokb)
{
    const int md = modeptr[0];
    int g = blockIdx.x * 256 + threadIdx.x;      // [0, 1048576)
    int t = g >> 5, dq = g & 31, d0 = dq * 4;
    int b = t >> 12, i = (t >> 6) & 63, j = t & 63;
    float v[4];
    if (i == j) {
        #pragma unroll
        for (int c = 0; c < 4; c++) v[c] = b2f(nodeB[d0 + c]);
        #pragma unroll
        for (int e = 0; e < 16; e++) {
            float xe = b2f(x[(b * 64 + i) * 16 + e]);
            #pragma unroll
            for (int c = 0; c < 4; c++) v[c] += xe * b2f(nodeW[e * 128 + d0 + c]);
        }
    } else {
        bool edge;
        if (md == 0)      edge = ((const u16*)mask)[t] != 0;
        else if (md == 3) edge = ((const float*)mask)[t] != 0.0f;
        else if (md == 1) edge = ((const unsigned char*)mask)[t] != 0;
        else              edge = ((const unsigned int*)mask)[t] != 0;
        if (edge) {
            #pragma unroll
            for (int c = 0; c < 4; c++) v[c] = b2f(edgeB[d0 + c]);
            #pragma unroll
            for (int e = 0; e < 8; e++) {
                float ae = b2f(ea[t * 8 + e]);
                #pragma unroll
                for (int c = 0; c < 4; c++) v[c] += ae * b2f(edgeW[e * 128 + d0 + c]);
            }
        } else {
            #pragma unroll
            for (int c = 0; c < 4; c++) v[c] = b2f(noedge[d0 + c]);
        }
    }
    *(float4*)(tokf + (size_t)t * 128 + d0) = make_float4(v[0], v[1], v[2], v[3]);
    u16 pk[4];
    #pragma unroll
    for (int c = 0; c < 4; c++) pk[c] = f2b(v[c]);
    *(uint2*)(tokb + (size_t)t * 128 + d0) = *(uint2*)pk;
}

// ---------------------------------------------------------------- generic GEMM
// modes: 1=bias+relu->bf16(outb), 2=bias+residual add into tokf, 3=qkv scatter
__global__ __launch_bounds__(256) void gemm_kernel(
    const u16* __restrict__ A, int lda,
    const u16* __restrict__ B0, const u16* __restrict__ B1,
    const u16* __restrict__ B2, const u16* __restrict__ B3,
    int ldb, const u16* __restrict__ bias,
    int K, int mode,
    u16* __restrict__ outb, int ldc,
    float* __restrict__ tokf,
    u16* __restrict__ qb, u16* __restrict__ kb, u16* __restrict__ v1b, u16* __restrict__ v2b)
{
    __shared__ __align__(16) u16 As[128 * 72];
    __shared__ __align__(16) u16 Bs[128 * 72];
    int tid = threadIdx.x;
    int m0 = blockIdx.x * 128;
    int by = blockIdx.y;
    const u16* Bp; int c0;
    if (mode == 3) { Bp = (by == 0) ? B0 : (by == 1) ? B1 : (by == 2) ? B2 : B3; c0 = 0; }
    else { Bp = B0; c0 = by * 128; }

    int w = tid >> 6, lane = tid & 63;
    int q = lane >> 4, r16 = lane & 15;
    int rw = (w >> 1) * 64, cw = (w & 1) * 64;

    f32x4 acc[4][4];
    #pragma unroll
    for (int mi = 0; mi < 4; mi++)
        #pragma unroll
        for (int ni = 0; ni < 4; ni++) acc[mi][ni] = (f32x4){0.f, 0.f, 0.f, 0.f};

    int nkt = K >> 6;
    for (int kt = 0; kt < nkt; ++kt) {
        int k0 = kt * 64;
        __syncthreads();
        #pragma unroll
        for (int it = 0; it < 4; ++it) {               // A: 128 x 64
            int idx = tid + it * 256;
            int row = idx >> 3, ch = idx & 7;
            uint4 d = *(const uint4*)(A + (size_t)(m0 + row) * lda + k0 + ch * 8);
            *(uint4*)&As[row * 72 + ch * 8] = d;
        }
        #pragma unroll
        for (int it = 0; it < 4; ++it) {               // B: 64 x 128 -> BT swizzled
            int idx = tid + it * 256;
            int kk = idx >> 4, nc = idx & 15;
            uint4 d = *(const uint4*)(Bp + (size_t)(k0 + kk) * ldb + c0 + nc * 8);
            const u16* ds = (const u16*)&d;
            int chunk = kk >> 3, kin = kk & 7;
            #pragma unroll
            for (int e = 0; e < 8; ++e) {
                int n = nc * 8 + e;
                int ch2 = chunk ^ ((n >> 3) & 7);
                Bs[n * 72 + ch2 * 8 + kin] = ds[e];
            }
        }
        __syncthreads();
        #pragma unroll
        for (int ks = 0; ks < 2; ++ks) {
            bf16x8 fa[4], fb[4];
            #pragma unroll
            for (int mi = 0; mi < 4; mi++)
                fa[mi] = *(const bf16x8*)&As[(rw + mi * 16 + r16) * 72 + ks * 32 + q * 8];
            #pragma unroll
            for (int ni = 0; ni < 4; ni++) {
                int n = cw + ni * 16 + r16;
                int ch2 = (ks * 4 + q) ^ ((n >> 3) & 7);
                fb[ni] = *(const bf16x8*)&Bs[n * 72 + ch2 * 8];
            }
            #pragma unroll
            for (int mi = 0; mi < 4; mi++)
                #pragma unroll
                for (int ni = 0; ni < 4; ni++)
                    acc[mi][ni] = __builtin_amdgcn_mfma_f32_16x16x32_bf16(fa[mi], fb[ni], acc[mi][ni], 0, 0, 0);
        }
    }

    #pragma unroll
    for (int mi = 0; mi < 4; mi++) {
        #pragma unroll
        for (int ni = 0; ni < 4; ni++) {
            int col = cw + ni * 16 + r16;
            #pragma unroll
            for (int rr = 0; rr < 4; rr++) {
                int row = m0 + rw + mi * 16 + q * 4 + rr;
                float v = acc[mi][ni][rr];
                if (mode == 1) {
                    v += b2f(bias[c0 + col]);
                    v = v > 0.f ? v : 0.f;
                    outb[(size_t)row * ldc + c0 + col] = f2b(v);
                } else if (mode == 2) {
                    v += b2f(bias[col]);
                    tokf[(size_t)row * 128 + col] += v;
                } else { // mode 3: qkv scatter
                    int bl = row >> 12, it_ = (row >> 6) & 63, jt = row & 63;
                    int h = col >> 5, d = col & 31;
                    size_t dst;
                    u16* dp;
                    if (by == 0) { dst = ((((size_t)(bl * 4 + h)) * 64 + jt) * 64 + it_) * 32 + d; dp = qb; }
                    else {
                        dst = ((((size_t)(bl * 4 + h)) * 64 + it_) * 64 + jt) * 32 + d;
                        dp = (by == 1) ? kb : (by == 2) ? v1b : v2b;
                    }
                    dp[dst] = f2b(v);
                }
            }
        }
    }
}

// ---------------------------------------------------------------- s = QK^T/scale (bf16 out)
__global__ __launch_bounds__(64) void attn_s_kernel(
    const u16* __restrict__ qb, const u16* __restrict__ kb, u16* __restrict__ s)
{
    __shared__ __align__(16) u16 qs[64 * 40];
    __shared__ __align__(16) u16 ks_[64 * 40];
    int g = blockIdx.x;
    int l = g & 63, bh = g >> 6;
    const u16* Q = qb + ((size_t)bh * 64 + l) * 2048;
    const u16* Kp = kb + ((size_t)bh * 64 + l) * 2048;
    int lane = threadIdx.x;
    #pragma unroll
    for (int it = 0; it < 4; ++it) {
        int idx = lane + it * 64;
        int row = idx >> 2, c4 = idx & 3;
        *(uint4*)&qs[row * 40 + c4 * 8] = *(const uint4*)(Q + row * 32 + c4 * 8);
        *(uint4*)&ks_[row * 40 + c4 * 8] = *(const uint4*)(Kp + row * 32 + c4 * 8);
    }
    __syncthreads();
    int q = lane >> 4, r16 = lane & 15;
    f32x4 acc[4][4];
    #pragma unroll
    for (int mi = 0; mi < 4; mi++)
        #pragma unroll
        for (int ni = 0; ni < 4; ni++) acc[mi][ni] = (f32x4){0.f, 0.f, 0.f, 0.f};
    bf16x8 fa[4], fb[4];
    #pragma unroll
    for (int mi = 0; mi < 4; mi++) fa[mi] = *(const bf16x8*)&qs[(mi * 16 + r16) * 40 + q * 8];
    #pragma unroll
    for (int ni = 0; ni < 4; ni++) fb[ni] = *(const bf16x8*)&ks_[(ni * 16 + r16) * 40 + q * 8];
    #pragma unroll
    for (int mi = 0; mi < 4; mi++)
        #pragma unroll
        for (int ni = 0; ni < 4; ni++)
            acc[mi][ni] = __builtin_amdgcn_mfma_f32_16x16x32_bf16(fa[mi], fb[ni], acc[mi][ni], 0, 0, 0);
    u16* sb = s + (size_t)bh * 262144 + l * 64;
    #pragma unroll
    for (int mi = 0; mi < 4; mi++)
        #pragma unroll
        for (int ni = 0; ni < 4; ni++)
            #pragma unroll
            for (int rr = 0; rr < 4; rr++) {
                int i = mi * 16 + q * 4 + rr, j = ni * 16 + r16;
                sb[(size_t)i * 4096 + j] = f2b(acc[mi][ni][rr] * INV_SCALE);
            }
}

// ---------------------------------------------------------------- fused softmax + o = sum_l a*v1*v2
// block = (bh, i-pair); threads (j=64) x (w=4): i=w&1, d-chunk=(w>>1)*16.
// v2 read direct from global (L1/L2-served, fully coalesced across waves);
// v1 staged once to LDS as f32 (wave-uniform broadcast reads); softmax held in r[64].
__global__ __launch_bounds__(256, 3) void attn_o_kernel(
    const u16* __restrict__ s, const u16* __restrict__ v1b, const u16* __restrict__ v2b,
    u16* __restrict__ ob)
{
    __shared__ __align__(16) float v1s[2 * 64 * 32];   // 16 KB
    int bid = blockIdx.x;
    int bh = bid >> 5, i0 = (bid & 31) * 2;
    int bl = bh >> 2, h = bh & 3;
    int tid = threadIdx.x, w = tid >> 6, j = tid & 63;
    int iw = w & 1;
    int dh = (w >> 1) * 16;
    const u16* v1base = v1b + (size_t)bh * 131072 + (size_t)i0 * 2048;
    const u16* v2base = v2b + (size_t)bh * 131072;
    const u16* sbase  = s + (size_t)bh * 262144;

    // stage v1[2i][64l][32d] bf16 -> f32 LDS (4096 elems)
    #pragma unroll
    for (int it = 0; it < 2; ++it) {
        int e0 = (tid + it * 256) * 8;
        uint4 d = *(const uint4*)(v1base + e0);
        const u16* ds = (const u16*)&d;
        float* dst = v1s + e0;
        #pragma unroll
        for (int e = 0; e < 8; e++) dst[e] = b2f(ds[e]);
    }

    // softmax over l for (i0+iw, j) — coalesced 128B loads per wave
    float r[64];
    {
        const u16* sp = sbase + (size_t)(i0 + iw) * 4096 + j;
        float mx = -1e30f;
        #pragma unroll
        for (int l = 0; l < 64; l++) { r[l] = b2f(sp[l * 64]); mx = fmaxf(mx, r[l]); }
        float sum = 0.f;
        #pragma unroll
        for (int l = 0; l < 64; l++) { r[l] = __expf(r[l] - mx); sum += r[l]; }
        float is = 1.0f / sum;
        #pragma unroll
        for (int l = 0; l < 64; l++) r[l] *= is;
    }
    __syncthreads();

    float acc[16];
    #pragma unroll
    for (int e = 0; e < 16; e++) acc[e] = 0.f;
    #pragma unroll 4
    for (int l = 0; l < 64; ++l) {
        const u16* vp = v2base + ((size_t)l * 64 + j) * 32 + dh;
        uint4 p0 = *(const uint4*)(vp);
        uint4 p1 = *(const uint4*)(vp + 8);
        const u16* vs0 = (const u16*)&p0;
        const u16* vs1 = (const u16*)&p1;
        float av = r[l];
        const float* v1p = v1s + (iw * 64 + l) * 32 + dh;
        #pragma unroll
        for (int e = 0; e < 8; e++) {
            acc[e]     += av * v1p[e]     * b2f(vs0[e]);
            acc[e + 8] += av * v1p[e + 8] * b2f(vs1[e]);
        }
    }
    u16 tmp[16];
    #pragma unroll
    for (int e = 0; e < 16; e++) tmp[e] = f2b(acc[e]);
    u16* op = ob + ((size_t)(bl * 64 + i0 + iw) * 64 + j) * 128 + h * 32 + dh;
    *(uint4*)op = *(uint4*)tmp;
    *(uint4*)(op + 8) = *(uint4*)&tmp[8];
}

// ---------------------------------------------------------------- LayerNorm
__global__ __launch_bounds__(256) void ln_kernel(
    float* __restrict__ tokf, u16* __restrict__ tokb,
    const u16* __restrict__ g, const u16* __restrict__ bp)
{
    int row = blockIdx.x * 4 + (threadIdx.x >> 6);
    int lane = threadIdx.x & 63;
    float* p = tokf + (size_t)row * 128 + lane * 2;
    float x0 = p[0], x1 = p[1];
    float s = x0 + x1, sq = x0 * x0 + x1 * x1;
    #pragma unroll
    for (int off = 32; off; off >>= 1) { s += __shfl_xor(s, off, 64); sq += __shfl_xor(sq, off, 64); }
    float mean = s * (1.0f / 128.0f);
    float var = sq * (1.0f / 128.0f) - mean * mean;
    float rs = rsqrtf(var + 1e-5f);
    float y0 = (x0 - mean) * rs * b2f(g[lane * 2]) + b2f(bp[lane * 2]);
    float y1 = (x1 - mean) * rs * b2f(g[lane * 2 + 1]) + b2f(bp[lane * 2 + 1]);
    p[0] = y0; p[1] = y1;
    unsigned int pk = (unsigned int)f2b(y0) | ((unsigned int)f2b(y1) << 16);
    *(unsigned int*)(tokb + (size_t)row * 128 + lane * 2) = pk;
}

// ---------------------------------------------------------------- final diag head (fp32 out)
__global__ __launch_bounds__(256) void out_kernel(
    const float* __restrict__ tokf, const u16* __restrict__ Wout, const u16* __restrict__ bout,
    float* __restrict__ out)
{
    int g = blockIdx.x * 256 + threadIdx.x;   // [0,512)
    int b = g >> 6, i = g & 63;
    const float* p = tokf + ((size_t)(b * 64 + i) * 64 + i) * 128;
    float s = b2f(bout[0]);
    #pragma unroll
    for (int d = 0; d < 128; d++) s += p[d] * b2f(Wout[d]);
    out[g] = s;
}

// ---------------------------------------------------------------- launch
extern "C" void kernel_launch(void* const* d_in, const int* in_sizes, int n_in,
                              void* d_out, int out_size, void* d_ws, size_t ws_size,
                              hipStream_t stream) {
    const void* mask = d_in[2];
    ParamPtrs pp;
    for (int k = 0; k < NSEG; ++k) pp.p[k] = d_in[k < 2 ? k : k + 1];   // skip mask

    char* ws = (char*)d_ws;
    u16* arena = (u16*)ws;
    #define AP(k) ((const u16*)ws + h_seg_off[k])
    int*   mmode = (int*)(ws + 1835008);
    float* tokf  = (float*)(ws + 2097152);      // 16 MB
    u16*   tokb  = (u16*)(ws + 18874368);       //  8 MB
    const size_t base = 27262976;

    // adaptive splits vs ws_size
    int NB = 8;
    while (NB > 1 && base + (size_t)NB * 6291456ULL > ws_size) NB >>= 1;
    int F = 1;
    while (F < 8 && base + (size_t)(32768 / F) * 1024ULL > ws_size) F <<= 1;

    size_t qSz = (size_t)NB * 1048576ULL;       // bytes per q/k/v buffer
    u16* qb  = (u16*)(ws + base);
    u16* kb  = (u16*)(ws + base + qSz);
    u16* v1b = (u16*)(ws + base + 2 * qSz);
    u16* v2b = (u16*)(ws + base + 3 * qSz);
    u16* sb  = (u16*)(ws + base + 4 * qSz);     // NB*2MB (bf16 raw scores)
    u16* ob  = qb;                              // q dead after attn_s
    u16* ffb = qb;                              // attention bufs dead in FF phase

    convert_params<<<1024, 256, 0, stream>>>(pp, arena);
    probe_kernel<<<1, 256, 0, stream>>>(mask, mmode);
    assemble_kernel<<<4096, 256, 0, stream>>>(AP(0), AP(1), mask, mmode,
                                              AP(2), AP(3), AP(4), AP(5), AP(6), tokf, tokb);

    for (int l = 0; l < 3; ++l) {
        const u16* Wq_l  = AP(7)  + l * 16384;
        const u16* Wk_l  = AP(8)  + l * 16384;
        const u16* Wv1_l = AP(9)  + l * 16384;
        const u16* Wv2_l = AP(10) + l * 16384;
        const u16* Wo_l  = AP(11) + l * 16384;
        const u16* bo_l  = AP(12) + l * 128;
        const u16* g1_l  = AP(13) + l * 128;
        const u16* be1_l = AP(14) + l * 128;
        const u16* W1_l  = AP(15) + l * 65536;
        const u16* b1_l  = AP(16) + l * 512;
        const u16* W2_l  = AP(17) + l * 65536;
        const u16* b2_l  = AP(18) + l * 128;
        const u16* g2_l  = AP(19) + l * 128;
        const u16* be2_l = AP(20) + l * 128;

        for (int r = 0; r < 8 / NB; ++r) {
            size_t rowOff = (size_t)r * NB * 4096;
            gemm_kernel<<<dim3(NB * 32, 4), 256, 0, stream>>>(
                tokb + rowOff * 128, 128, Wq_l, Wk_l, Wv1_l, Wv2_l,
                128, (const u16*)0, 128, 3, (u16*)0, 0, (float*)0, qb, kb, v1b, v2b);
            attn_s_kernel<<<NB * 256, 64, 0, stream>>>(qb, kb, sb);
            attn_o_kernel<<<NB * 128, 256, 0, stream>>>(sb, v1b, v2b, ob);
            gemm_kernel<<<dim3(NB * 32, 1), 256, 0, stream>>>(
                ob, 128, Wo_l, (const u16*)0, (const u16*)0, (const u16*)0,
                128, bo_l, 128, 2, (u16*)0, 0, tokf + rowOff * 128,
                (u16*)0, (u16*)0, (u16*)0, (u16*)0);
        }
        ln_kernel<<<8192, 256, 0, stream>>>(tokf, tokb, g1_l, be1_l);
        for (int f = 0; f < F; ++f) {
            size_t r0 = (size_t)f * (32768 / F);
            int RB = (32768 / F) / 128;
            gemm_kernel<<<dim3(RB, 4), 256, 0, stream>>>(
                tokb + r0 * 128, 128, W1_l, (const u16*)0, (const u16*)0, (const u16*)0,
                512, b1_l, 128, 1, ffb, 512, (float*)0, (u16*)0, (u16*)0, (u16*)0, (u16*)0);
            gemm_kernel<<<dim3(RB, 1), 256, 0, stream>>>(
                ffb, 512, W2_l, (const u16*)0, (const u16*)0, (const u16*)0,
                128, b2_l, 512, 2, (u16*)0, 0, tokf + r0 * 128,
                (u16*)0, (u16*)0, (u16*)0, (u16*)0);
        }
        ln_kernel<<<8192, 256, 0, stream>>>(tokf, tokb, g2_l, be2_l);
    }
    out_kernel<<<2, 256, 0, stream>>>(tokf, AP(21), AP(22), (float*)d_out);
}

// Round 6
// 777.727 us; speedup vs baseline: 1.0082x; 1.0082x over previous
//
#include <hip/hip_runtime.h>

typedef unsigned short u16;
typedef __attribute__((ext_vector_type(8))) short bf16x8;
typedef __attribute__((ext_vector_type(4))) float f32x4;

#define INV_SCALE 0.17677669529663687f

static __device__ __forceinline__ float b2f(u16 u) {
    union { unsigned int i; float f; } v; v.i = ((unsigned int)u) << 16; return v.f;
}
static __device__ __forceinline__ u16 f2b(float f) {
    union { float f; unsigned int i; } v; v.f = f;
    unsigned int r = (v.i + 0x7FFFu + ((v.i >> 16) & 1u)) >> 16;
    return (u16)r;
}

// ---- param arena segment table (bf16 elements), shared host/device ----
#define NSEG 23
__device__ __constant__ int d_seg_off[NSEG + 1] = {
    0, 8192, 270336, 272384, 272512, 273536, 273664, 273792, 322944, 372096,
    421248, 470400, 519552, 519936, 520320, 520704, 717312, 718848, 915456,
    915840, 916224, 916608, 916736, 916744};
static const int h_seg_off[NSEG + 1] = {
    0, 8192, 270336, 272384, 272512, 273536, 273664, 273792, 322944, 372096,
    421248, 470400, 519552, 519936, 520320, 520704, 717312, 718848, 915456,
    915840, 916224, 916608, 916736, 916744};
#define ARENA_TOTAL 916744

struct ParamPtrs { const void* p[NSEG]; };

// ---------------------------------------------------------------- param convert
__global__ __launch_bounds__(256) void convert_params(ParamPtrs pp, u16* __restrict__ arena) {
    const unsigned int probe = ((const unsigned int*)pp.p[13])[0];   // ln1_g[0] == 1.0
    const bool f32 = (probe == 0x3F800000u);
    for (int e = blockIdx.x * 256 + threadIdx.x; e < ARENA_TOTAL; e += gridDim.x * 256) {
        int k = 0;
        #pragma unroll
        for (int s2 = 1; s2 < NSEG; ++s2) if (e >= d_seg_off[s2]) k = s2;
        int local = e - d_seg_off[k];
        u16 v;
        if (k == 22 && local >= 1) v = 0;   // bout padded 1 -> 8
        else v = f32 ? f2b(((const float*)pp.p[k])[local]) : ((const u16*)pp.p[k])[local];
        arena[e] = v;
    }
}

// ---------------------------------------------------------------- mask dtype probe (tiny)
__global__ __launch_bounds__(256) void probe_kernel(const void* mask, int* __restrict__ mode) {
    __shared__ int f16, f32s, u8s;
    int tid = threadIdx.x;
    if (tid == 0) { f16 = 0; f32s = 0; u8s = 0; }
    __syncthreads();
    const u16* mu = (const u16*)mask;
    const unsigned int* mw = (const unsigned int*)mask;
    if (mu[2 * tid] == 0x3F80u) atomicOr(&f16, 1);
    if (mw[tid] == 0x3F800000u) atomicOr(&f32s, 1);
    if (mw[tid] > 1u) atomicOr(&u8s, 1);
    __syncthreads();
    if (tid == 0) mode[0] = f16 ? 0 : (f32s ? 3 : (u8s ? 1 : 2));
}

// ---------------------------------------------------------------- tok assembly (mask fused)
__global__ __launch_bounds__(256) void assemble_kernel(
    const u16* __restrict__ x, const u16* __restrict__ ea,
    const void* __restrict__ mask, const int* __restrict__ modeptr,
    const u16* __restrict__ nodeW, const u16* __restrict__ nodeB,
    const u16* __restrict__ edgeW, const u16* __restrict__ edgeB, const u16* __restrict__ noedge,
    float* __restrict__ tokf, u16* __restrict__ tokb)
{
    const int md = modeptr[0];
    int g = blockIdx.x * 256 + threadIdx.x;      // [0, 1048576)
    int t = g >> 5, dq = g & 31, d0 = dq * 4;
    int b = t >> 12, i = (t >> 6) & 63, j = t & 63;
    float v[4];
    if (i == j) {
        #pragma unroll
        for (int c = 0; c < 4; c++) v[c] = b2f(nodeB[d0 + c]);
        #pragma unroll
        for (int e = 0; e < 16; e++) {
            float xe = b2f(x[(b * 64 + i) * 16 + e]);
            #pragma unroll
            for (int c = 0; c < 4; c++) v[c] += xe * b2f(nodeW[e * 128 + d0 + c]);
        }
    } else {
        bool edge;
        if (md == 0)      edge = ((const u16*)mask)[t] != 0;
        else if (md == 3) edge = ((const float*)mask)[t] != 0.0f;
        else if (md == 1) edge = ((const unsigned char*)mask)[t] != 0;
        else              edge = ((const unsigned int*)mask)[t] != 0;
        if (edge) {
            #pragma unroll
            for (int c = 0; c < 4; c++) v[c] = b2f(edgeB[d0 + c]);
            #pragma unroll
            for (int e = 0; e < 8; e++) {
                float ae = b2f(ea[t * 8 + e]);
                #pragma unroll
                for (int c = 0; c < 4; c++) v[c] += ae * b2f(edgeW[e * 128 + d0 + c]);
            }
        } else {
            #pragma unroll
            for (int c = 0; c < 4; c++) v[c] = b2f(noedge[d0 + c]);
        }
    }
    *(float4*)(tokf + (size_t)t * 128 + d0) = make_float4(v[0], v[1], v[2], v[3]);
    u16 pk[4];
    #pragma unroll
    for (int c = 0; c < 4; c++) pk[c] = f2b(v[c]);
    *(uint2*)(tokb + (size_t)t * 128 + d0) = *(uint2*)pk;
}

// ---------------------------------------------------------------- generic GEMM
// modes: 1=bias+relu->bf16(outb), 2=bias+residual add into tokf, 3=qkv scatter
// mode 3: by==2 (v1) writes FP32 into tokf (= v1f buffer); others bf16.
__global__ __launch_bounds__(256) void gemm_kernel(
    const u16* __restrict__ A, int lda,
    const u16* __restrict__ B0, const u16* __restrict__ B1,
    const u16* __restrict__ B2, const u16* __restrict__ B3,
    int ldb, const u16* __restrict__ bias,
    int K, int mode,
    u16* __restrict__ outb, int ldc,
    float* __restrict__ tokf,
    u16* __restrict__ qb, u16* __restrict__ kb, u16* __restrict__ v2b)
{
    __shared__ __align__(16) u16 As[128 * 72];
    __shared__ __align__(16) u16 Bs[128 * 72];
    int tid = threadIdx.x;
    int m0 = blockIdx.x * 128;
    int by = blockIdx.y;
    const u16* Bp; int c0;
    if (mode == 3) { Bp = (by == 0) ? B0 : (by == 1) ? B1 : (by == 2) ? B2 : B3; c0 = 0; }
    else { Bp = B0; c0 = by * 128; }

    int w = tid >> 6, lane = tid & 63;
    int q = lane >> 4, r16 = lane & 15;
    int rw = (w >> 1) * 64, cw = (w & 1) * 64;

    f32x4 acc[4][4];
    #pragma unroll
    for (int mi = 0; mi < 4; mi++)
        #pragma unroll
        for (int ni = 0; ni < 4; ni++) acc[mi][ni] = (f32x4){0.f, 0.f, 0.f, 0.f};

    int nkt = K >> 6;
    for (int kt = 0; kt < nkt; ++kt) {
        int k0 = kt * 64;
        __syncthreads();
        #pragma unroll
        for (int it = 0; it < 4; ++it) {               // A: 128 x 64
            int idx = tid + it * 256;
            int row = idx >> 3, ch = idx & 7;
            uint4 d = *(const uint4*)(A + (size_t)(m0 + row) * lda + k0 + ch * 8);
            *(uint4*)&As[row * 72 + ch * 8] = d;
        }
        #pragma unroll
        for (int it = 0; it < 4; ++it) {               // B: 64 x 128 -> BT swizzled
            int idx = tid + it * 256;
            int kk = idx >> 4, nc = idx & 15;
            uint4 d = *(const uint4*)(Bp + (size_t)(k0 + kk) * ldb + c0 + nc * 8);
            const u16* ds = (const u16*)&d;
            int chunk = kk >> 3, kin = kk & 7;
            #pragma unroll
            for (int e = 0; e < 8; ++e) {
                int n = nc * 8 + e;
                int ch2 = chunk ^ ((n >> 3) & 7);
                Bs[n * 72 + ch2 * 8 + kin] = ds[e];
            }
        }
        __syncthreads();
        #pragma unroll
        for (int ks = 0; ks < 2; ++ks) {
            bf16x8 fa[4], fb[4];
            #pragma unroll
            for (int mi = 0; mi < 4; mi++)
                fa[mi] = *(const bf16x8*)&As[(rw + mi * 16 + r16) * 72 + ks * 32 + q * 8];
            #pragma unroll
            for (int ni = 0; ni < 4; ni++) {
                int n = cw + ni * 16 + r16;
                int ch2 = (ks * 4 + q) ^ ((n >> 3) & 7);
                fb[ni] = *(const bf16x8*)&Bs[n * 72 + ch2 * 8];
            }
            #pragma unroll
            for (int mi = 0; mi < 4; mi++)
                #pragma unroll
                for (int ni = 0; ni < 4; ni++)
                    acc[mi][ni] = __builtin_amdgcn_mfma_f32_16x16x32_bf16(fa[mi], fb[ni], acc[mi][ni], 0, 0, 0);
        }
    }

    #pragma unroll
    for (int mi = 0; mi < 4; mi++) {
        #pragma unroll
        for (int ni = 0; ni < 4; ni++) {
            int col = cw + ni * 16 + r16;
            #pragma unroll
            for (int rr = 0; rr < 4; rr++) {
                int row = m0 + rw + mi * 16 + q * 4 + rr;
                float v = acc[mi][ni][rr];
                if (mode == 1) {
                    v += b2f(bias[c0 + col]);
                    v = v > 0.f ? v : 0.f;
                    outb[(size_t)row * ldc + c0 + col] = f2b(v);
                } else if (mode == 2) {
                    v += b2f(bias[col]);
                    tokf[(size_t)row * 128 + col] += v;
                } else { // mode 3: qkv scatter
                    int bl = row >> 12, it_ = (row >> 6) & 63, jt = row & 63;
                    int h = col >> 5, d = col & 31;
                    if (by == 0) {
                        qb[((((size_t)(bl * 4 + h)) * 64 + jt) * 64 + it_) * 32 + d] = f2b(v);
                    } else if (by == 1) {
                        kb[((((size_t)(bl * 4 + h)) * 64 + it_) * 64 + jt) * 32 + d] = f2b(v);
                    } else if (by == 2) {   // v1 -> fp32 (tokf = v1f)
                        tokf[((((size_t)(bl * 4 + h)) * 64 + it_) * 64 + jt) * 32 + d] = v;
                    } else {
                        v2b[((((size_t)(bl * 4 + h)) * 64 + it_) * 64 + jt) * 32 + d] = f2b(v);
                    }
                }
            }
        }
    }
}

// ---------------------------------------------------------------- s = QK^T/scale (bf16 out)
__global__ __launch_bounds__(64) void attn_s_kernel(
    const u16* __restrict__ qb, const u16* __restrict__ kb, u16* __restrict__ s)
{
    __shared__ __align__(16) u16 qs[64 * 40];
    __shared__ __align__(16) u16 ks_[64 * 40];
    int g = blockIdx.x;
    int l = g & 63, bh = g >> 6;
    const u16* Q = qb + ((size_t)bh * 64 + l) * 2048;
    const u16* Kp = kb + ((size_t)bh * 64 + l) * 2048;
    int lane = threadIdx.x;
    #pragma unroll
    for (int it = 0; it < 4; ++it) {
        int idx = lane + it * 64;
        int row = idx >> 2, c4 = idx & 3;
        *(uint4*)&qs[row * 40 + c4 * 8] = *(const uint4*)(Q + row * 32 + c4 * 8);
        *(uint4*)&ks_[row * 40 + c4 * 8] = *(const uint4*)(Kp + row * 32 + c4 * 8);
    }
    __syncthreads();
    int q = lane >> 4, r16 = lane & 15;
    f32x4 acc[4][4];
    #pragma unroll
    for (int mi = 0; mi < 4; mi++)
        #pragma unroll
        for (int ni = 0; ni < 4; ni++) acc[mi][ni] = (f32x4){0.f, 0.f, 0.f, 0.f};
    bf16x8 fa[4], fb[4];
    #pragma unroll
    for (int mi = 0; mi < 4; mi++) fa[mi] = *(const bf16x8*)&qs[(mi * 16 + r16) * 40 + q * 8];
    #pragma unroll
    for (int ni = 0; ni < 4; ni++) fb[ni] = *(const bf16x8*)&ks_[(ni * 16 + r16) * 40 + q * 8];
    #pragma unroll
    for (int mi = 0; mi < 4; mi++)
        #pragma unroll
        for (int ni = 0; ni < 4; ni++)
            acc[mi][ni] = __builtin_amdgcn_mfma_f32_16x16x32_bf16(fa[mi], fb[ni], acc[mi][ni], 0, 0, 0);
    u16* sb = s + (size_t)bh * 262144 + l * 64;
    #pragma unroll
    for (int mi = 0; mi < 4; mi++)
        #pragma unroll
        for (int ni = 0; ni < 4; ni++)
            #pragma unroll
            for (int rr = 0; rr < 4; rr++) {
                int i = mi * 16 + q * 4 + rr, j = ni * 16 + r16;
                sb[(size_t)i * 4096 + j] = f2b(acc[mi][ni][rr] * INV_SCALE);
            }
}

// ---------------------------------------------------------------- softmax over l (bf16 in/out)
__global__ __launch_bounds__(256) void softmax_kernel(u16* __restrict__ s) {
    int g = blockIdx.x * 256 + threadIdx.x;
    int j = g & 63, bhi = g >> 6;
    u16* p = s + (size_t)bhi * 4096 + j;
    float r[64];
    float mx = -1e30f;
    #pragma unroll
    for (int l = 0; l < 64; l++) { r[l] = b2f(p[l * 64]); mx = fmaxf(mx, r[l]); }
    float sum = 0.f;
    #pragma unroll
    for (int l = 0; l < 64; l++) { r[l] = __expf(r[l] - mx); sum += r[l]; }
    float is = 1.0f / sum;
    #pragma unroll
    for (int l = 0; l < 64; l++) p[l * 64] = f2b(r[l] * is);
}

// ---------------------------------------------------------------- o = sum_l a*v1*v2
// grid (NB*4 = bh, 8 = i-group). v2 in LDS fp32 (stride 36 floats, conflict-free),
// v1 fp32 via wave-uniform scalar loads, a via coalesced L1-hot global reads.
__global__ __launch_bounds__(256) void attn_o_kernel(
    const u16* __restrict__ a, const float* __restrict__ v1f, const u16* __restrict__ v2b,
    u16* __restrict__ ob)
{
    __shared__ __align__(16) float v2s[4 * 2304];    // 36864 B; reused as u16 os[8*64*36]
    int bh = blockIdx.x;
    int i0 = blockIdx.y * 8;
    int bl = bh >> 2, h = bh & 3;
    int tid = threadIdx.x;
    int w = __builtin_amdgcn_readfirstlane(tid >> 6);
    int j = tid & 63;
    int dh = w * 8;
    const float* v1base = v1f + ((size_t)bh * 64 + i0) * 2048 + dh;   // [i][l][32]
    const u16* v2base = v2b + (size_t)bh * 131072;
    const u16* abase  = a + (size_t)bh * 262144 + (size_t)i0 * 4096 + j;

    float acc[8][8];
    #pragma unroll
    for (int i = 0; i < 8; i++)
        #pragma unroll
        for (int e = 0; e < 8; e++) acc[i][e] = 0.f;

    for (int ch = 0; ch < 16; ++ch) {
        int l0 = ch * 4;
        __syncthreads();
        #pragma unroll
        for (int it = 0; it < 4; ++it) {             // stage v2: 4l x 64j x 32d -> fp32
            int idx = tid + it * 256;                // (l:2 | j:6 | c4:2)
            int ll = idx >> 8, jj = (idx >> 2) & 63, c4 = idx & 3;
            uint4 d = *(const uint4*)(v2base + ((size_t)(l0 + ll) * 64 + jj) * 32 + c4 * 8);
            const u16* ds = (const u16*)&d;
            float* dst = &v2s[ll * 2304 + jj * 36 + c4 * 8];
            #pragma unroll
            for (int e = 0; e < 8; e++) dst[e] = b2f(ds[e]);
        }
        __syncthreads();
        #pragma unroll
        for (int lc = 0; lc < 4; ++lc) {
            int l = l0 + lc;
            const float* vp = &v2s[lc * 2304 + j * 36 + dh];
            float v2r[8];
            *(f32x4*)&v2r[0] = *(const f32x4*)vp;
            *(f32x4*)&v2r[4] = *(const f32x4*)(vp + 4);
            #pragma unroll
            for (int i = 0; i < 8; i++) {
                float av = b2f(abase[(size_t)i * 4096 + l * 64]);
                const float* v1p = v1base + ((size_t)i * 64 + l) * 32;   // uniform addr
                #pragma unroll
                for (int e = 0; e < 8; e++)
                    acc[i][e] += (av * v1p[e]) * v2r[e];
            }
        }
    }

    // epilogue: LDS transpose -> coalesced full-line writes
    __syncthreads();
    u16* os = (u16*)v2s;                             // [i][j][stride 36]
    #pragma unroll
    for (int i = 0; i < 8; i++) {
        u16 tmp[8];
        #pragma unroll
        for (int e = 0; e < 8; e++) tmp[e] = f2b(acc[i][e]);
        u16* d = &os[((size_t)i * 64 + j) * 36 + dh];
        *(uint2*)d = *(uint2*)&tmp[0];
        *(uint2*)(d + 4) = *(uint2*)&tmp[4];
    }
    __syncthreads();
    #pragma unroll
    for (int it = 0; it < 8; ++it) {
        int idx = tid + it * 256;                    // (i:3 | j:6 | c:2)
        int i = idx >> 8, jj = (idx >> 2) & 63, c = idx & 3;
        const u16* src = &os[((size_t)i * 64 + jj) * 36 + c * 8];
        uint2 lo = *(const uint2*)src;
        uint2 hi = *(const uint2*)(src + 4);
        u16* dst = ob + ((size_t)(bl * 64 + i0 + i) * 64 + jj) * 128 + h * 32 + c * 8;
        *(uint2*)dst = lo;
        *(uint2*)(dst + 4) = hi;
    }
}

// ---------------------------------------------------------------- LayerNorm
__global__ __launch_bounds__(256) void ln_kernel(
    float* __restrict__ tokf, u16* __restrict__ tokb,
    const u16* __restrict__ g, const u16* __restrict__ bp)
{
    int row = blockIdx.x * 4 + (threadIdx.x >> 6);
    int lane = threadIdx.x & 63;
    float* p = tokf + (size_t)row * 128 + lane * 2;
    float x0 = p[0], x1 = p[1];
    float s = x0 + x1, sq = x0 * x0 + x1 * x1;
    #pragma unroll
    for (int off = 32; off; off >>= 1) { s += __shfl_xor(s, off, 64); sq += __shfl_xor(sq, off, 64); }
    float mean = s * (1.0f / 128.0f);
    float var = sq * (1.0f / 128.0f) - mean * mean;
    float rs = rsqrtf(var + 1e-5f);
    float y0 = (x0 - mean) * rs * b2f(g[lane * 2]) + b2f(bp[lane * 2]);
    float y1 = (x1 - mean) * rs * b2f(g[lane * 2 + 1]) + b2f(bp[lane * 2 + 1]);
    p[0] = y0; p[1] = y1;
    unsigned int pk = (unsigned int)f2b(y0) | ((unsigned int)f2b(y1) << 16);
    *(unsigned int*)(tokb + (size_t)row * 128 + lane * 2) = pk;
}

// ---------------------------------------------------------------- final diag head (fp32 out)
__global__ __launch_bounds__(256) void out_kernel(
    const float* __restrict__ tokf, const u16* __restrict__ Wout, const u16* __restrict__ bout,
    float* __restrict__ out)
{
    int g = blockIdx.x * 256 + threadIdx.x;   // [0,512)
    int b = g >> 6, i = g & 63;
    const float* p = tokf + ((size_t)(b * 64 + i) * 64 + i) * 128;
    float s = b2f(bout[0]);
    #pragma unroll
    for (int d = 0; d < 128; d++) s += p[d] * b2f(Wout[d]);
    out[g] = s;
}

// ---------------------------------------------------------------- launch
extern "C" void kernel_launch(void* const* d_in, const int* in_sizes, int n_in,
                              void* d_out, int out_size, void* d_ws, size_t ws_size,
                              hipStream_t stream) {
    const void* mask = d_in[2];
    ParamPtrs pp;
    for (int k = 0; k < NSEG; ++k) pp.p[k] = d_in[k < 2 ? k : k + 1];   // skip mask

    char* ws = (char*)d_ws;
    u16* arena = (u16*)ws;
    #define AP(k) ((const u16*)ws + h_seg_off[k])
    int*   mmode = (int*)(ws + 1835008);
    float* tokf  = (float*)(ws + 2097152);      // 16 MB
    u16*   tokb  = (u16*)(ws + 18874368);       //  8 MB
    const size_t base = 27262976;
    const size_t MB = 1048576ULL;

    // adaptive splits vs ws_size: attn needs base + 7*NB MB
    int NB = 8;
    while (NB > 1 && base + (size_t)NB * 7 * MB > ws_size) NB >>= 1;
    int F = 1;
    while (F < 8 && base + (size_t)(32768 / F) * 1024ULL > ws_size) F <<= 1;

    u16*   qb  = (u16*)(ws + base);                       // NB MB
    u16*   kb  = (u16*)(ws + base + (size_t)NB * MB);     // NB MB
    u16*   v2b = (u16*)(ws + base + (size_t)NB * 2 * MB); // NB MB
    float* v1f = (float*)(ws + base + (size_t)NB * 3 * MB); // 2*NB MB
    u16*   sb  = (u16*)(ws + base + (size_t)NB * 5 * MB);   // 2*NB MB
    u16*   ob  = qb;                              // q dead after attn_s
    u16*   ffb = qb;                              // attention bufs dead in FF phase

    convert_params<<<1024, 256, 0, stream>>>(pp, arena);
    probe_kernel<<<1, 256, 0, stream>>>(mask, mmode);
    assemble_kernel<<<4096, 256, 0, stream>>>(AP(0), AP(1), mask, mmode,
                                              AP(2), AP(3), AP(4), AP(5), AP(6), tokf, tokb);

    for (int l = 0; l < 3; ++l) {
        const u16* Wq_l  = AP(7)  + l * 16384;
        const u16* Wk_l  = AP(8)  + l * 16384;
        const u16* Wv1_l = AP(9)  + l * 16384;
        const u16* Wv2_l = AP(10) + l * 16384;
        const u16* Wo_l  = AP(11) + l * 16384;
        const u16* bo_l  = AP(12) + l * 128;
        const u16* g1_l  = AP(13) + l * 128;
        const u16* be1_l = AP(14) + l * 128;
        const u16* W1_l  = AP(15) + l * 65536;
        const u16* b1_l  = AP(16) + l * 512;
        const u16* W2_l  = AP(17) + l * 65536;
        const u16* b2_l  = AP(18) + l * 128;
        const u16* g2_l  = AP(19) + l * 128;
        const u16* be2_l = AP(20) + l * 128;

        for (int r = 0; r < 8 / NB; ++r) {
            size_t rowOff = (size_t)r * NB * 4096;
            gemm_kernel<<<dim3(NB * 32, 4), 256, 0, stream>>>(
                tokb + rowOff * 128, 128, Wq_l, Wk_l, Wv1_l, Wv2_l,
                128, (const u16*)0, 128, 3, (u16*)0, 0, v1f, qb, kb, v2b);
            attn_s_kernel<<<NB * 256, 64, 0, stream>>>(qb, kb, sb);
            softmax_kernel<<<NB * 64, 256, 0, stream>>>(sb);
            attn_o_kernel<<<dim3(NB * 4, 8), 256, 0, stream>>>(sb, v1f, v2b, ob);
            gemm_kernel<<<dim3(NB * 32, 1), 256, 0, stream>>>(
                ob, 128, Wo_l, (const u16*)0, (const u16*)0, (const u16*)0,
                128, bo_l, 128, 2, (u16*)0, 0, tokf + rowOff * 128,
                (u16*)0, (u16*)0, (u16*)0);
        }
        ln_kernel<<<8192, 256, 0, stream>>>(tokf, tokb, g1_l, be1_l);
        for (int f = 0; f < F; ++f) {
            size_t r0 = (size_t)f * (32768 / F);
            int RB = (32768 / F) / 128;
            gemm_kernel<<<dim3(RB, 4), 256, 0, stream>>>(
                tokb + r0 * 128, 128, W1_l, (const u16*)0, (const u16*)0, (const u16*)0,
                512, b1_l, 128, 1, ffb, 512, (float*)0, (u16*)0, (u16*)0, (u16*)0);
            gemm_kernel<<<dim3(RB, 1), 256, 0, stream>>>(
                ffb, 512, W2_l, (const u16*)0, (const u16*)0, (const u16*)0,
                128, b2_l, 512, 2, (u16*)0, 0, tokf + r0 * 128,
                (u16*)0, (u16*)0, (u16*)0);
        }
        ln_kernel<<<8192, 256, 0, stream>>>(tokf, tokb, g2_l, be2_l);
    }
    out_kernel<<<2, 256, 0, stream>>>(tokf, AP(21), AP(22), (float*)d_out);
}

// Round 7
// 707.578 us; speedup vs baseline: 1.1081x; 1.0991x over previous
//
#include <hip/hip_runtime.h>

typedef unsigned short u16;
typedef __attribute__((ext_vector_type(8))) short bf16x8;
typedef __attribute__((ext_vector_type(4))) float f32x4;

#define INV_SCALE 0.17677669529663687f

static __device__ __forceinline__ float b2f(u16 u) {
    union { unsigned int i; float f; } v; v.i = ((unsigned int)u) << 16; return v.f;
}
static __device__ __forceinline__ u16 f2b(float f) {
    union { float f; unsigned int i; } v; v.f = f;
    unsigned int r = (v.i + 0x7FFFu + ((v.i >> 16) & 1u)) >> 16;
    return (u16)r;
}

// ---- param arena segment table (bf16 elements), shared host/device ----
#define NSEG 23
__device__ __constant__ int d_seg_off[NSEG + 1] = {
    0, 8192, 270336, 272384, 272512, 273536, 273664, 273792, 322944, 372096,
    421248, 470400, 519552, 519936, 520320, 520704, 717312, 718848, 915456,
    915840, 916224, 916608, 916736, 916744};
static const int h_seg_off[NSEG + 1] = {
    0, 8192, 270336, 272384, 272512, 273536, 273664, 273792, 322944, 372096,
    421248, 470400, 519552, 519936, 520320, 520704, 717312, 718848, 915456,
    915840, 916224, 916608, 916736, 916744};
#define ARENA_TOTAL 916744

struct ParamPtrs { const void* p[NSEG]; };

// ---------------------------------------------------------------- param convert
__global__ __launch_bounds__(256) void convert_params(ParamPtrs pp, u16* __restrict__ arena) {
    const unsigned int probe = ((const unsigned int*)pp.p[13])[0];   // ln1_g[0] == 1.0
    const bool f32 = (probe == 0x3F800000u);
    for (int e = blockIdx.x * 256 + threadIdx.x; e < ARENA_TOTAL; e += gridDim.x * 256) {
        int k = 0;
        #pragma unroll
        for (int s2 = 1; s2 < NSEG; ++s2) if (e >= d_seg_off[s2]) k = s2;
        int local = e - d_seg_off[k];
        u16 v;
        if (k == 22 && local >= 1) v = 0;   // bout padded 1 -> 8
        else v = f32 ? f2b(((const float*)pp.p[k])[local]) : ((const u16*)pp.p[k])[local];
        arena[e] = v;
    }
}

// ---------------------------------------------------------------- mask dtype probe (tiny)
__global__ __launch_bounds__(256) void probe_kernel(const void* mask, int* __restrict__ mode) {
    __shared__ int f16, f32s, u8s;
    int tid = threadIdx.x;
    if (tid == 0) { f16 = 0; f32s = 0; u8s = 0; }
    __syncthreads();
    const u16* mu = (const u16*)mask;
    const unsigned int* mw = (const unsigned int*)mask;
    if (mu[2 * tid] == 0x3F80u) atomicOr(&f16, 1);
    if (mw[tid] == 0x3F800000u) atomicOr(&f32s, 1);
    if (mw[tid] > 1u) atomicOr(&u8s, 1);
    __syncthreads();
    if (tid == 0) mode[0] = f16 ? 0 : (f32s ? 3 : (u8s ? 1 : 2));
}

// ---------------------------------------------------------------- tok assembly (mask fused)
__global__ __launch_bounds__(256) void assemble_kernel(
    const u16* __restrict__ x, const u16* __restrict__ ea,
    const void* __restrict__ mask, const int* __restrict__ modeptr,
    const u16* __restrict__ nodeW, const u16* __restrict__ nodeB,
    const u16* __restrict__ edgeW, const u16* __restrict__ edgeB, const u16* __restrict__ noedge,
    float* __restrict__ tokf, u16* __restrict__ tokb)
{
    const int md = modeptr[0];
    int g = blockIdx.x * 256 + threadIdx.x;      // [0, 1048576)
    int t = g >> 5, dq = g & 31, d0 = dq * 4;
    int b = t >> 12, i = (t >> 6) & 63, j = t & 63;
    float v[4];
    if (i == j) {
        #pragma unroll
        for (int c = 0; c < 4; c++) v[c] = b2f(nodeB[d0 + c]);
        #pragma unroll
        for (int e = 0; e < 16; e++) {
            float xe = b2f(x[(b * 64 + i) * 16 + e]);
            #pragma unroll
            for (int c = 0; c < 4; c++) v[c] += xe * b2f(nodeW[e * 128 + d0 + c]);
        }
    } else {
        bool edge;
        if (md == 0)      edge = ((const u16*)mask)[t] != 0;
        else if (md == 3) edge = ((const float*)mask)[t] != 0.0f;
        else if (md == 1) edge = ((const unsigned char*)mask)[t] != 0;
        else              edge = ((const unsigned int*)mask)[t] != 0;
        if (edge) {
            #pragma unroll
            for (int c = 0; c < 4; c++) v[c] = b2f(edgeB[d0 + c]);
            #pragma unroll
            for (int e = 0; e < 8; e++) {
                float ae = b2f(ea[t * 8 + e]);
                #pragma unroll
                for (int c = 0; c < 4; c++) v[c] += ae * b2f(edgeW[e * 128 + d0 + c]);
            }
        } else {
            #pragma unroll
            for (int c = 0; c < 4; c++) v[c] = b2f(noedge[d0 + c]);
        }
    }
    *(float4*)(tokf + (size_t)t * 128 + d0) = make_float4(v[0], v[1], v[2], v[3]);
    u16 pk[4];
    #pragma unroll
    for (int c = 0; c < 4; c++) pk[c] = f2b(v[c]);
    *(uint2*)(tokb + (size_t)t * 128 + d0) = *(uint2*)pk;
}

// ---------------------------------------------------------------- generic GEMM
// modes: 1=bias+relu->bf16(outb), 2=bias+residual add into tokf, 3=qkv scatter
// mode 3: by==2 (v1) writes FP32 into tokf (= v1f buffer); others bf16.
// Epilogue: LDS transpose (XOR-swizzled) -> coalesced vector stores.
__global__ __launch_bounds__(256) void gemm_kernel(
    const u16* __restrict__ A, int lda,
    const u16* __restrict__ B0, const u16* __restrict__ B1,
    const u16* __restrict__ B2, const u16* __restrict__ B3,
    int ldb, const u16* __restrict__ bias,
    int K, int mode,
    u16* __restrict__ outb, int ldc,
    float* __restrict__ tokf,
    u16* __restrict__ qb, u16* __restrict__ kb, u16* __restrict__ v2b)
{
    __shared__ __align__(16) u16 smem[2 * 128 * 72];   // 36864 B
    u16* As = smem;
    u16* Bs = smem + 128 * 72;
    int tid = threadIdx.x;
    int m0 = blockIdx.x * 128;
    int by = blockIdx.y;
    const u16* Bp; int c0;
    if (mode == 3) { Bp = (by == 0) ? B0 : (by == 1) ? B1 : (by == 2) ? B2 : B3; c0 = 0; }
    else { Bp = B0; c0 = by * 128; }

    int w = tid >> 6, lane = tid & 63;
    int q = lane >> 4, r16 = lane & 15;
    int rw = (w >> 1) * 64, cw = (w & 1) * 64;

    f32x4 acc[4][4];
    #pragma unroll
    for (int mi = 0; mi < 4; mi++)
        #pragma unroll
        for (int ni = 0; ni < 4; ni++) acc[mi][ni] = (f32x4){0.f, 0.f, 0.f, 0.f};

    int nkt = K >> 6;
    for (int kt = 0; kt < nkt; ++kt) {
        int k0 = kt * 64;
        __syncthreads();
        #pragma unroll
        for (int it = 0; it < 4; ++it) {               // A: 128 x 64
            int idx = tid + it * 256;
            int row = idx >> 3, ch = idx & 7;
            uint4 d = *(const uint4*)(A + (size_t)(m0 + row) * lda + k0 + ch * 8);
            *(uint4*)&As[row * 72 + ch * 8] = d;
        }
        #pragma unroll
        for (int it = 0; it < 4; ++it) {               // B: 64 x 128 -> BT swizzled
            int idx = tid + it * 256;
            int kk = idx >> 4, nc = idx & 15;
            uint4 d = *(const uint4*)(Bp + (size_t)(k0 + kk) * ldb + c0 + nc * 8);
            const u16* ds = (const u16*)&d;
            int chunk = kk >> 3, kin = kk & 7;
            #pragma unroll
            for (int e = 0; e < 8; ++e) {
                int n = nc * 8 + e;
                int ch2 = chunk ^ ((n >> 3) & 7);
                Bs[n * 72 + ch2 * 8 + kin] = ds[e];
            }
        }
        __syncthreads();
        #pragma unroll
        for (int ks = 0; ks < 2; ++ks) {
            bf16x8 fa[4], fb[4];
            #pragma unroll
            for (int mi = 0; mi < 4; mi++)
                fa[mi] = *(const bf16x8*)&As[(rw + mi * 16 + r16) * 72 + ks * 32 + q * 8];
            #pragma unroll
            for (int ni = 0; ni < 4; ni++) {
                int n = cw + ni * 16 + r16;
                int ch2 = (ks * 4 + q) ^ ((n >> 3) & 7);
                fb[ni] = *(const bf16x8*)&Bs[n * 72 + ch2 * 8];
            }
            #pragma unroll
            for (int mi = 0; mi < 4; mi++)
                #pragma unroll
                for (int ni = 0; ni < 4; ni++)
                    acc[mi][ni] = __builtin_amdgcn_mfma_f32_16x16x32_bf16(fa[mi], fb[ni], acc[mi][ni], 0, 0, 0);
        }
    }

    // ---------------- epilogue: LDS transpose, coalesced stores ----------------
    int bl = m0 >> 12, it0 = (m0 >> 6) & 63;
    bool fp32path = (mode == 2) || (mode == 3 && by == 2);
    __syncthreads();
    if (!fp32path) {
        u16* cs = smem;                                // [128][128] u16, XOR-swizzled
        #pragma unroll
        for (int mi = 0; mi < 4; mi++) {
            #pragma unroll
            for (int ni = 0; ni < 4; ni++) {
                int col = cw + ni * 16 + r16;
                int ch = col >> 3, cl = col & 7;
                #pragma unroll
                for (int rr = 0; rr < 4; rr++) {
                    int r = rw + mi * 16 + q * 4 + rr;
                    float v = acc[mi][ni][rr];
                    if (mode == 1) { v += b2f(bias[c0 + col]); v = fmaxf(v, 0.f); }
                    cs[r * 128 + (((ch ^ (r & 15)) << 3) | cl)] = f2b(v);
                }
            }
        }
        __syncthreads();
        if (mode == 1) {
            #pragma unroll
            for (int it = 0; it < 8; ++it) {
                int idx = tid + it * 256;              // (r:7 | c8:4)
                int r = idx >> 4, c8 = idx & 15;
                uint4 d = *(const uint4*)&cs[r * 128 + ((c8 ^ (r & 15)) << 3)];
                *(uint4*)&outb[(size_t)(m0 + r) * ldc + c0 + c8 * 8] = d;
            }
        } else if (by == 0) {                          // q: [bh][l=jt][i=it][32]
            #pragma unroll
            for (int it = 0; it < 8; ++it) {
                int idx = tid + it * 256;              // (h:2 | jt:6 | itl:1 | d8:2)
                int h = idx >> 9, jt = (idx >> 3) & 63, itl = (idx >> 2) & 1, d8 = idx & 3;
                int r = itl * 64 + jt, c8 = h * 4 + d8;
                uint4 d = *(const uint4*)&cs[r * 128 + ((c8 ^ (r & 15)) << 3)];
                *(uint4*)&qb[((((size_t)(bl * 4 + h)) * 64 + jt) * 64 + it0 + itl) * 32 + d8 * 8] = d;
            }
        } else {                                       // k / v2: [bh][i=it][j=jt][32]
            u16* dp = (by == 1) ? kb : v2b;
            #pragma unroll
            for (int it = 0; it < 8; ++it) {
                int idx = tid + it * 256;              // (h:2 | itl:1 | jt:6 | d8:2)
                int h = idx >> 9, itl = (idx >> 8) & 1, jt = (idx >> 2) & 63, d8 = idx & 3;
                int r = itl * 64 + jt, c8 = h * 4 + d8;
                uint4 d = *(const uint4*)&cs[r * 128 + ((c8 ^ (r & 15)) << 3)];
                *(uint4*)&dp[((((size_t)(bl * 4 + h)) * 64 + it0 + itl) * 64 + jt) * 32 + d8 * 8] = d;
            }
        }
    } else {
        float* cf = (float*)smem;                      // [128][64] fp32, XOR-swizzled
        #pragma unroll
        for (int hp = 0; hp < 2; ++hp) {
            if (hp) __syncthreads();
            if ((cw >> 6) == hp) {                     // wave-uniform: this wave's cols in this half
                #pragma unroll
                for (int mi = 0; mi < 4; mi++) {
                    #pragma unroll
                    for (int ni = 0; ni < 4; ni++) {
                        int colh = (cw & 63) + ni * 16 + r16;
                        int ch4 = colh >> 2, cl = colh & 3;
                        #pragma unroll
                        for (int rr = 0; rr < 4; rr++) {
                            int r = rw + mi * 16 + q * 4 + rr;
                            cf[r * 64 + (((ch4 ^ (r & 15)) << 2) | cl)] = acc[mi][ni][rr];
                        }
                    }
                }
            }
            __syncthreads();
            if (mode == 2) {                           // residual RMW into tokf
                #pragma unroll
                for (int it = 0; it < 8; ++it) {
                    int idx = tid + it * 256;          // (r:7 | c4:4)
                    int r = idx >> 4, c4 = idx & 15;
                    f32x4 v = *(const f32x4*)&cf[r * 64 + ((c4 ^ (r & 15)) << 2)];
                    int col = hp * 64 + c4 * 4;
                    float* tp = tokf + (size_t)(m0 + r) * 128 + col;
                    f32x4 t = *(const f32x4*)tp;
                    #pragma unroll
                    for (int e = 0; e < 4; e++) t[e] += v[e] + b2f(bias[col + e]);
                    *(f32x4*)tp = t;
                }
            } else {                                   // v1f fp32: [bh][i=it][l=jt][32]
                #pragma unroll
                for (int it = 0; it < 8; ++it) {
                    int idx = tid + it * 256;          // (hh:1 | itl:1 | jt:6 | d4:3)
                    int hh = idx >> 10, itl = (idx >> 9) & 1, jt = (idx >> 3) & 63, d4 = idx & 7;
                    int r = itl * 64 + jt;
                    int colh = hh * 32 + d4 * 4;
                    f32x4 v = *(const f32x4*)&cf[r * 64 + (((colh >> 2) ^ (r & 15)) << 2)];
                    int h = hp * 2 + hh;
                    *(f32x4*)&tokf[((((size_t)(bl * 4 + h)) * 64 + it0 + itl) * 64 + jt) * 32 + d4 * 4] = v;
                }
            }
        }
    }
}

// ---------------------------------------------------------------- s = QK^T/scale (bf16 out)
__global__ __launch_bounds__(64) void attn_s_kernel(
    const u16* __restrict__ qb, const u16* __restrict__ kb, u16* __restrict__ s)
{
    __shared__ __align__(16) u16 qs[64 * 40];
    __shared__ __align__(16) u16 ks_[64 * 40];
    int g = blockIdx.x;
    int l = g & 63, bh = g >> 6;
    const u16* Q = qb + ((size_t)bh * 64 + l) * 2048;
    const u16* Kp = kb + ((size_t)bh * 64 + l) * 2048;
    int lane = threadIdx.x;
    #pragma unroll
    for (int it = 0; it < 4; ++it) {
        int idx = lane + it * 64;
        int row = idx >> 2, c4 = idx & 3;
        *(uint4*)&qs[row * 40 + c4 * 8] = *(const uint4*)(Q + row * 32 + c4 * 8);
        *(uint4*)&ks_[row * 40 + c4 * 8] = *(const uint4*)(Kp + row * 32 + c4 * 8);
    }
    __syncthreads();
    int q = lane >> 4, r16 = lane & 15;
    f32x4 acc[4][4];
    #pragma unroll
    for (int mi = 0; mi < 4; mi++)
        #pragma unroll
        for (int ni = 0; ni < 4; ni++) acc[mi][ni] = (f32x4){0.f, 0.f, 0.f, 0.f};
    bf16x8 fa[4], fb[4];
    #pragma unroll
    for (int mi = 0; mi < 4; mi++) fa[mi] = *(const bf16x8*)&qs[(mi * 16 + r16) * 40 + q * 8];
    #pragma unroll
    for (int ni = 0; ni < 4; ni++) fb[ni] = *(const bf16x8*)&ks_[(ni * 16 + r16) * 40 + q * 8];
    #pragma unroll
    for (int mi = 0; mi < 4; mi++)
        #pragma unroll
        for (int ni = 0; ni < 4; ni++)
            acc[mi][ni] = __builtin_amdgcn_mfma_f32_16x16x32_bf16(fa[mi], fb[ni], acc[mi][ni], 0, 0, 0);
    u16* sb = s + (size_t)bh * 262144 + l * 64;
    #pragma unroll
    for (int mi = 0; mi < 4; mi++)
        #pragma unroll
        for (int ni = 0; ni < 4; ni++)
            #pragma unroll
            for (int rr = 0; rr < 4; rr++) {
                int i = mi * 16 + q * 4 + rr, j = ni * 16 + r16;
                sb[(size_t)i * 4096 + j] = f2b(acc[mi][ni][rr] * INV_SCALE);
            }
}

// ---------------------------------------------------------------- softmax over l (bf16 in/out)
__global__ __launch_bounds__(256) void softmax_kernel(u16* __restrict__ s) {
    int g = blockIdx.x * 256 + threadIdx.x;
    int j = g & 63, bhi = g >> 6;
    u16* p = s + (size_t)bhi * 4096 + j;
    float r[64];
    float mx = -1e30f;
    #pragma unroll
    for (int l = 0; l < 64; l++) { r[l] = b2f(p[l * 64]); mx = fmaxf(mx, r[l]); }
    float sum = 0.f;
    #pragma unroll
    for (int l = 0; l < 64; l++) { r[l] = __expf(r[l] - mx); sum += r[l]; }
    float is = 1.0f / sum;
    #pragma unroll
    for (int l = 0; l < 64; l++) p[l * 64] = f2b(r[l] * is);
}

// ---------------------------------------------------------------- o = sum_l a*v1*v2
// grid (bh, 16 groups of 4 i). v2 in LDS fp32 (stride 36, conflict-free per R6 PMC),
// v1 fp32 wave-uniform scalar loads, a coalesced global reads.
__global__ __launch_bounds__(256) void attn_o_kernel(
    const u16* __restrict__ a, const float* __restrict__ v1f, const u16* __restrict__ v2b,
    u16* __restrict__ ob)
{
    __shared__ __align__(16) float v2s[4 * 2304];    // 36864 B; reused as u16 os[4*64*36]
    int bh = blockIdx.x;
    int i0 = blockIdx.y * 4;
    int bl = bh >> 2, h = bh & 3;
    int tid = threadIdx.x;
    int w = __builtin_amdgcn_readfirstlane(tid >> 6);
    int j = tid & 63;
    int dh = w * 8;
    const float* v1base = v1f + ((size_t)bh * 64 + i0) * 2048 + dh;   // [i][l][32]
    const u16* v2base = v2b + (size_t)bh * 131072;
    const u16* abase  = a + (size_t)bh * 262144 + (size_t)i0 * 4096 + j;

    float acc[4][8];
    #pragma unroll
    for (int i = 0; i < 4; i++)
        #pragma unroll
        for (int e = 0; e < 8; e++) acc[i][e] = 0.f;

    for (int ch = 0; ch < 16; ++ch) {
        int l0 = ch * 4;
        __syncthreads();
        #pragma unroll
        for (int it = 0; it < 4; ++it) {             // stage v2: 4l x 64j x 32d -> fp32
            int idx = tid + it * 256;                // (l:2 | j:6 | c4:2)
            int ll = idx >> 8, jj = (idx >> 2) & 63, c4 = idx & 3;
            uint4 d = *(const uint4*)(v2base + ((size_t)(l0 + ll) * 64 + jj) * 32 + c4 * 8);
            const u16* ds = (const u16*)&d;
            float* dst = &v2s[ll * 2304 + jj * 36 + c4 * 8];
            #pragma unroll
            for (int e = 0; e < 8; e++) dst[e] = b2f(ds[e]);
        }
        __syncthreads();
        #pragma unroll
        for (int lc = 0; lc < 4; ++lc) {
            int l = l0 + lc;
            const float* vp = &v2s[lc * 2304 + j * 36 + dh];
            float v2r[8];
            *(f32x4*)&v2r[0] = *(const f32x4*)vp;
            *(f32x4*)&v2r[4] = *(const f32x4*)(vp + 4);
            #pragma unroll
            for (int i = 0; i < 4; i++) {
                float av = b2f(abase[(size_t)i * 4096 + l * 64]);
                const float* v1p = v1base + ((size_t)i * 64 + l) * 32;   // uniform addr
                #pragma unroll
                for (int e = 0; e < 8; e++)
                    acc[i][e] += (av * v1p[e]) * v2r[e];
            }
        }
    }

    // epilogue: LDS transpose -> coalesced full-line writes
    __syncthreads();
    u16* os = (u16*)v2s;                             // [i][j][stride 36]
    #pragma unroll
    for (int i = 0; i < 4; i++) {
        u16 tmp[8];
        #pragma unroll
        for (int e = 0; e < 8; e++) tmp[e] = f2b(acc[i][e]);
        u16* d = &os[((size_t)i * 64 + j) * 36 + dh];
        *(uint2*)d = *(uint2*)&tmp[0];
        *(uint2*)(d + 4) = *(uint2*)&tmp[4];
    }
    __syncthreads();
    #pragma unroll
    for (int it = 0; it < 4; ++it) {
        int idx = tid + it * 256;                    // (i:2 | j:6 | c:2)
        int i = idx >> 8, jj = (idx >> 2) & 63, c = idx & 3;
        const u16* src = &os[((size_t)i * 64 + jj) * 36 + c * 8];
        uint2 lo = *(const uint2*)src;
        uint2 hi = *(const uint2*)(src + 4);
        u16* dst = ob + ((size_t)(bl * 64 + i0 + i) * 64 + jj) * 128 + h * 32 + c * 8;
        *(uint2*)dst = lo;
        *(uint2*)(dst + 4) = hi;
    }
}

// ---------------------------------------------------------------- LayerNorm
__global__ __launch_bounds__(256) void ln_kernel(
    float* __restrict__ tokf, u16* __restrict__ tokb,
    const u16* __restrict__ g, const u16* __restrict__ bp)
{
    int row = blockIdx.x * 4 + (threadIdx.x >> 6);
    int lane = threadIdx.x & 63;
    float* p = tokf + (size_t)row * 128 + lane * 2;
    float x0 = p[0], x1 = p[1];
    float s = x0 + x1, sq = x0 * x0 + x1 * x1;
    #pragma unroll
    for (int off = 32; off; off >>= 1) { s += __shfl_xor(s, off, 64); sq += __shfl_xor(sq, off, 64); }
    float mean = s * (1.0f / 128.0f);
    float var = sq * (1.0f / 128.0f) - mean * mean;
    float rs = rsqrtf(var + 1e-5f);
    float y0 = (x0 - mean) * rs * b2f(g[lane * 2]) + b2f(bp[lane * 2]);
    float y1 = (x1 - mean) * rs * b2f(g[lane * 2 + 1]) + b2f(bp[lane * 2 + 1]);
    p[0] = y0; p[1] = y1;
    unsigned int pk = (unsigned int)f2b(y0) | ((unsigned int)f2b(y1) << 16);
    *(unsigned int*)(tokb + (size_t)row * 128 + lane * 2) = pk;
}

// ---------------------------------------------------------------- final diag head (fp32 out)
__global__ __launch_bounds__(256) void out_kernel(
    const float* __restrict__ tokf, const u16* __restrict__ Wout, const u16* __restrict__ bout,
    float* __restrict__ out)
{
    int g = blockIdx.x * 256 + threadIdx.x;   // [0,512)
    int b = g >> 6, i = g & 63;
    const float* p = tokf + ((size_t)(b * 64 + i) * 64 + i) * 128;
    float s = b2f(bout[0]);
    #pragma unroll
    for (int d = 0; d < 128; d++) s += p[d] * b2f(Wout[d]);
    out[g] = s;
}

// ---------------------------------------------------------------- launch
extern "C" void kernel_launch(void* const* d_in, const int* in_sizes, int n_in,
                              void* d_out, int out_size, void* d_ws, size_t ws_size,
                              hipStream_t stream) {
    const void* mask = d_in[2];
    ParamPtrs pp;
    for (int k = 0; k < NSEG; ++k) pp.p[k] = d_in[k < 2 ? k : k + 1];   // skip mask

    char* ws = (char*)d_ws;
    u16* arena = (u16*)ws;
    #define AP(k) ((const u16*)ws + h_seg_off[k])
    int*   mmode = (int*)(ws + 1835008);
    float* tokf  = (float*)(ws + 2097152);      // 16 MB
    u16*   tokb  = (u16*)(ws + 18874368);       //  8 MB
    const size_t base = 27262976;
    const size_t MB = 1048576ULL;

    // adaptive splits vs ws_size: attn needs base + 7*NB MB
    int NB = 8;
    while (NB > 1 && base + (size_t)NB * 7 * MB > ws_size) NB >>= 1;
    int F = 1;
    while (F < 8 && base + (size_t)(32768 / F) * 1024ULL > ws_size) F <<= 1;

    u16*   qb  = (u16*)(ws + base);                       // NB MB
    u16*   kb  = (u16*)(ws + base + (size_t)NB * MB);     // NB MB
    u16*   v2b = (u16*)(ws + base + (size_t)NB * 2 * MB); // NB MB
    float* v1f = (float*)(ws + base + (size_t)NB * 3 * MB); // 2*NB MB
    u16*   sb  = (u16*)(ws + base + (size_t)NB * 5 * MB);   // 2*NB MB
    u16*   ob  = qb;                              // q dead after attn_s
    u16*   ffb = qb;                              // attention bufs dead in FF phase

    convert_params<<<1024, 256, 0, stream>>>(pp, arena);
    probe_kernel<<<1, 256, 0, stream>>>(mask, mmode);
    assemble_kernel<<<4096, 256, 0, stream>>>(AP(0), AP(1), mask, mmode,
                                              AP(2), AP(3), AP(4), AP(5), AP(6), tokf, tokb);

    for (int l = 0; l < 3; ++l) {
        const u16* Wq_l  = AP(7)  + l * 16384;
        const u16* Wk_l  = AP(8)  + l * 16384;
        const u16* Wv1_l = AP(9)  + l * 16384;
        const u16* Wv2_l = AP(10) + l * 16384;
        const u16* Wo_l  = AP(11) + l * 16384;
        const u16* bo_l  = AP(12) + l * 128;
        const u16* g1_l  = AP(13) + l * 128;
        const u16* be1_l = AP(14) + l * 128;
        const u16* W1_l  = AP(15) + l * 65536;
        const u16* b1_l  = AP(16) + l * 512;
        const u16* W2_l  = AP(17) + l * 65536;
        const u16* b2_l  = AP(18) + l * 128;
        const u16* g2_l  = AP(19) + l * 128;
        const u16* be2_l = AP(20) + l * 128;

        for (int r = 0; r < 8 / NB; ++r) {
            size_t rowOff = (size_t)r * NB * 4096;
            gemm_kernel<<<dim3(NB * 32, 4), 256, 0, stream>>>(
                tokb + rowOff * 128, 128, Wq_l, Wk_l, Wv1_l, Wv2_l,
                128, (const u16*)0, 128, 3, (u16*)0, 0, v1f, qb, kb, v2b);
            attn_s_kernel<<<NB * 256, 64, 0, stream>>>(qb, kb, sb);
            softmax_kernel<<<NB * 64, 256, 0, stream>>>(sb);
            attn_o_kernel<<<dim3(NB * 4, 16), 256, 0, stream>>>(sb, v1f, v2b, ob);
            gemm_kernel<<<dim3(NB * 32, 1), 256, 0, stream>>>(
                ob, 128, Wo_l, (const u16*)0, (const u16*)0, (const u16*)0,
                128, bo_l, 128, 2, (u16*)0, 0, tokf + rowOff * 128,
                (u16*)0, (u16*)0, (u16*)0);
        }
        ln_kernel<<<8192, 256, 0, stream>>>(tokf, tokb, g1_l, be1_l);
        for (int f = 0; f < F; ++f) {
            size_t r0 = (size_t)f * (32768 / F);
            int RB = (32768 / F) / 128;
            gemm_kernel<<<dim3(RB, 4), 256, 0, stream>>>(
                tokb + r0 * 128, 128, W1_l, (const u16*)0, (const u16*)0, (const u16*)0,
                512, b1_l, 128, 1, ffb, 512, (float*)0, (u16*)0, (u16*)0, (u16*)0);
            gemm_kernel<<<dim3(RB, 1), 256, 0, stream>>>(
                ffb, 512, W2_l, (const u16*)0, (const u16*)0, (const u16*)0,
                128, b2_l, 512, 2, (u16*)0, 0, tokf + r0 * 128,
                (u16*)0, (u16*)0, (u16*)0);
        }
        ln_kernel<<<8192, 256, 0, stream>>>(tokf, tokb, g2_l, be2_l);
    }
    out_kernel<<<2, 256, 0, stream>>>(tokf, AP(21), AP(22), (float*)d_out);
}

// Round 8
// 573.109 us; speedup vs baseline: 1.3681x; 1.2346x over previous
//
#include <hip/hip_runtime.h>

typedef unsigned short u16;
typedef __attribute__((ext_vector_type(8))) short bf16x8;
typedef __attribute__((ext_vector_type(4))) float f32x4;

#define INV_SCALE 0.17677669529663687f

static __device__ __forceinline__ float b2f(u16 u) {
    union { unsigned int i; float f; } v; v.i = ((unsigned int)u) << 16; return v.f;
}
static __device__ __forceinline__ u16 f2b(float f) {
    union { float f; unsigned int i; } v; v.f = f;
    unsigned int r = (v.i + 0x7FFFu + ((v.i >> 16) & 1u)) >> 16;
    return (u16)r;
}

// ---- param arena segment table (bf16 elements), shared host/device ----
#define NSEG 23
__device__ __constant__ int d_seg_off[NSEG + 1] = {
    0, 8192, 270336, 272384, 272512, 273536, 273664, 273792, 322944, 372096,
    421248, 470400, 519552, 519936, 520320, 520704, 717312, 718848, 915456,
    915840, 916224, 916608, 916736, 916744};
static const int h_seg_off[NSEG + 1] = {
    0, 8192, 270336, 272384, 272512, 273536, 273664, 273792, 322944, 372096,
    421248, 470400, 519552, 519936, 520320, 520704, 717312, 718848, 915456,
    915840, 916224, 916608, 916736, 916744};
#define ARENA_TOTAL 916744

struct ParamPtrs { const void* p[NSEG]; };

// ---------------------------------------------------------------- param convert
__global__ __launch_bounds__(256) void convert_params(ParamPtrs pp, u16* __restrict__ arena) {
    const unsigned int probe = ((const unsigned int*)pp.p[13])[0];   // ln1_g[0] == 1.0
    const bool f32 = (probe == 0x3F800000u);
    for (int e = blockIdx.x * 256 + threadIdx.x; e < ARENA_TOTAL; e += gridDim.x * 256) {
        int k = 0;
        #pragma unroll
        for (int s2 = 1; s2 < NSEG; ++s2) if (e >= d_seg_off[s2]) k = s2;
        int local = e - d_seg_off[k];
        u16 v;
        if (k == 22 && local >= 1) v = 0;   // bout padded 1 -> 8
        else v = f32 ? f2b(((const float*)pp.p[k])[local]) : ((const u16*)pp.p[k])[local];
        arena[e] = v;
    }
}

// ---------------------------------------------------------------- mask dtype probe (tiny)
__global__ __launch_bounds__(256) void probe_kernel(const void* mask, int* __restrict__ mode) {
    __shared__ int f16, f32s, u8s;
    int tid = threadIdx.x;
    if (tid == 0) { f16 = 0; f32s = 0; u8s = 0; }
    __syncthreads();
    const u16* mu = (const u16*)mask;
    const unsigned int* mw = (const unsigned int*)mask;
    if (mu[2 * tid] == 0x3F80u) atomicOr(&f16, 1);
    if (mw[tid] == 0x3F800000u) atomicOr(&f32s, 1);
    if (mw[tid] > 1u) atomicOr(&u8s, 1);
    __syncthreads();
    if (tid == 0) mode[0] = f16 ? 0 : (f32s ? 3 : (u8s ? 1 : 2));
}

// ---------------------------------------------------------------- tok assembly (mask fused)
__global__ __launch_bounds__(256) void assemble_kernel(
    const u16* __restrict__ x, const u16* __restrict__ ea,
    const void* __restrict__ mask, const int* __restrict__ modeptr,
    const u16* __restrict__ nodeW, const u16* __restrict__ nodeB,
    const u16* __restrict__ edgeW, const u16* __restrict__ edgeB, const u16* __restrict__ noedge,
    float* __restrict__ tokf, u16* __restrict__ tokb)
{
    const int md = modeptr[0];
    int g = blockIdx.x * 256 + threadIdx.x;      // [0, 1048576)
    int t = g >> 5, dq = g & 31, d0 = dq * 4;
    int b = t >> 12, i = (t >> 6) & 63, j = t & 63;
    float v[4];
    if (i == j) {
        #pragma unroll
        for (int c = 0; c < 4; c++) v[c] = b2f(nodeB[d0 + c]);
        #pragma unroll
        for (int e = 0; e < 16; e++) {
            float xe = b2f(x[(b * 64 + i) * 16 + e]);
            #pragma unroll
            for (int c = 0; c < 4; c++) v[c] += xe * b2f(nodeW[e * 128 + d0 + c]);
        }
    } else {
        bool edge;
        if (md == 0)      edge = ((const u16*)mask)[t] != 0;
        else if (md == 3) edge = ((const float*)mask)[t] != 0.0f;
        else if (md == 1) edge = ((const unsigned char*)mask)[t] != 0;
        else              edge = ((const unsigned int*)mask)[t] != 0;
        if (edge) {
            #pragma unroll
            for (int c = 0; c < 4; c++) v[c] = b2f(edgeB[d0 + c]);
            #pragma unroll
            for (int e = 0; e < 8; e++) {
                float ae = b2f(ea[t * 8 + e]);
                #pragma unroll
                for (int c = 0; c < 4; c++) v[c] += ae * b2f(edgeW[e * 128 + d0 + c]);
            }
        } else {
            #pragma unroll
            for (int c = 0; c < 4; c++) v[c] = b2f(noedge[d0 + c]);
        }
    }
    *(float4*)(tokf + (size_t)t * 128 + d0) = make_float4(v[0], v[1], v[2], v[3]);
    u16 pk[4];
    #pragma unroll
    for (int c = 0; c < 4; c++) pk[c] = f2b(v[c]);
    *(uint2*)(tokb + (size_t)t * 128 + d0) = *(uint2*)pk;
}

// ---------------------------------------------------------------- generic GEMM
// modes: 1=bias+relu->bf16(outb), 2=bias+residual add into tokf, 3=qkv scatter
// mode 3: by==2 (v1) writes FP32 into tokf (= v1f buffer); others bf16.
// Epilogue: LDS transpose (XOR-swizzled) -> coalesced vector stores.
__global__ __launch_bounds__(256) void gemm_kernel(
    const u16* __restrict__ A, int lda,
    const u16* __restrict__ B0, const u16* __restrict__ B1,
    const u16* __restrict__ B2, const u16* __restrict__ B3,
    int ldb, const u16* __restrict__ bias,
    int K, int mode,
    u16* __restrict__ outb, int ldc,
    float* __restrict__ tokf,
    u16* __restrict__ qb, u16* __restrict__ kb, u16* __restrict__ v2b)
{
    __shared__ __align__(16) u16 smem[2 * 128 * 72];   // 36864 B
    u16* As = smem;
    u16* Bs = smem + 128 * 72;
    int tid = threadIdx.x;
    int m0 = blockIdx.x * 128;
    int by = blockIdx.y;
    const u16* Bp; int c0;
    if (mode == 3) { Bp = (by == 0) ? B0 : (by == 1) ? B1 : (by == 2) ? B2 : B3; c0 = 0; }
    else { Bp = B0; c0 = by * 128; }

    int w = tid >> 6, lane = tid & 63;
    int q = lane >> 4, r16 = lane & 15;
    int rw = (w >> 1) * 64, cw = (w & 1) * 64;

    f32x4 acc[4][4];
    #pragma unroll
    for (int mi = 0; mi < 4; mi++)
        #pragma unroll
        for (int ni = 0; ni < 4; ni++) acc[mi][ni] = (f32x4){0.f, 0.f, 0.f, 0.f};

    int nkt = K >> 6;
    for (int kt = 0; kt < nkt; ++kt) {
        int k0 = kt * 64;
        __syncthreads();
        #pragma unroll
        for (int it = 0; it < 4; ++it) {               // A: 128 x 64
            int idx = tid + it * 256;
            int row = idx >> 3, ch = idx & 7;
            uint4 d = *(const uint4*)(A + (size_t)(m0 + row) * lda + k0 + ch * 8);
            *(uint4*)&As[row * 72 + ch * 8] = d;
        }
        #pragma unroll
        for (int it = 0; it < 4; ++it) {               // B: 64 x 128 -> BT swizzled
            int idx = tid + it * 256;
            int kk = idx >> 4, nc = idx & 15;
            uint4 d = *(const uint4*)(Bp + (size_t)(k0 + kk) * ldb + c0 + nc * 8);
            const u16* ds = (const u16*)&d;
            int chunk = kk >> 3, kin = kk & 7;
            #pragma unroll
            for (int e = 0; e < 8; ++e) {
                int n = nc * 8 + e;
                int ch2 = chunk ^ ((n >> 3) & 7);
                Bs[n * 72 + ch2 * 8 + kin] = ds[e];
            }
        }
        __syncthreads();
        #pragma unroll
        for (int ks = 0; ks < 2; ++ks) {
            bf16x8 fa[4], fb[4];
            #pragma unroll
            for (int mi = 0; mi < 4; mi++)
                fa[mi] = *(const bf16x8*)&As[(rw + mi * 16 + r16) * 72 + ks * 32 + q * 8];
            #pragma unroll
            for (int ni = 0; ni < 4; ni++) {
                int n = cw + ni * 16 + r16;
                int ch2 = (ks * 4 + q) ^ ((n >> 3) & 7);
                fb[ni] = *(const bf16x8*)&Bs[n * 72 + ch2 * 8];
            }
            #pragma unroll
            for (int mi = 0; mi < 4; mi++)
                #pragma unroll
                for (int ni = 0; ni < 4; ni++)
                    acc[mi][ni] = __builtin_amdgcn_mfma_f32_16x16x32_bf16(fa[mi], fb[ni], acc[mi][ni], 0, 0, 0);
        }
    }

    // ---------------- epilogue: LDS transpose, coalesced stores ----------------
    int bl = m0 >> 12, it0 = (m0 >> 6) & 63;
    bool fp32path = (mode == 2) || (mode == 3 && by == 2);
    __syncthreads();
    if (!fp32path) {
        u16* cs = smem;                                // [128][128] u16, XOR-swizzled
        #pragma unroll
        for (int mi = 0; mi < 4; mi++) {
            #pragma unroll
            for (int ni = 0; ni < 4; ni++) {
                int col = cw + ni * 16 + r16;
                int ch = col >> 3, cl = col & 7;
                #pragma unroll
                for (int rr = 0; rr < 4; rr++) {
                    int r = rw + mi * 16 + q * 4 + rr;
                    float v = acc[mi][ni][rr];
                    if (mode == 1) { v += b2f(bias[c0 + col]); v = fmaxf(v, 0.f); }
                    cs[r * 128 + (((ch ^ (r & 15)) << 3) | cl)] = f2b(v);
                }
            }
        }
        __syncthreads();
        if (mode == 1) {
            #pragma unroll
            for (int it = 0; it < 8; ++it) {
                int idx = tid + it * 256;              // (r:7 | c8:4)
                int r = idx >> 4, c8 = idx & 15;
                uint4 d = *(const uint4*)&cs[r * 128 + ((c8 ^ (r & 15)) << 3)];
                *(uint4*)&outb[(size_t)(m0 + r) * ldc + c0 + c8 * 8] = d;
            }
        } else if (by == 0) {                          // q: [bh][l=jt][i=it][32]
            #pragma unroll
            for (int it = 0; it < 8; ++it) {
                int idx = tid + it * 256;              // (h:2 | jt:6 | itl:1 | d8:2)
                int h = idx >> 9, jt = (idx >> 3) & 63, itl = (idx >> 2) & 1, d8 = idx & 3;
                int r = itl * 64 + jt, c8 = h * 4 + d8;
                uint4 d = *(const uint4*)&cs[r * 128 + ((c8 ^ (r & 15)) << 3)];
                *(uint4*)&qb[((((size_t)(bl * 4 + h)) * 64 + jt) * 64 + it0 + itl) * 32 + d8 * 8] = d;
            }
        } else {                                       // k / v2: [bh][i=it][j=jt][32]
            u16* dp = (by == 1) ? kb : v2b;
            #pragma unroll
            for (int it = 0; it < 8; ++it) {
                int idx = tid + it * 256;              // (h:2 | itl:1 | jt:6 | d8:2)
                int h = idx >> 9, itl = (idx >> 8) & 1, jt = (idx >> 2) & 63, d8 = idx & 3;
                int r = itl * 64 + jt, c8 = h * 4 + d8;
                uint4 d = *(const uint4*)&cs[r * 128 + ((c8 ^ (r & 15)) << 3)];
                *(uint4*)&dp[((((size_t)(bl * 4 + h)) * 64 + it0 + itl) * 64 + jt) * 32 + d8 * 8] = d;
            }
        }
    } else {
        float* cf = (float*)smem;                      // [128][64] fp32, XOR-swizzled
        #pragma unroll
        for (int hp = 0; hp < 2; ++hp) {
            if (hp) __syncthreads();
            if ((cw >> 6) == hp) {                     // wave-uniform: this wave's cols in this half
                #pragma unroll
                for (int mi = 0; mi < 4; mi++) {
                    #pragma unroll
                    for (int ni = 0; ni < 4; ni++) {
                        int colh = (cw & 63) + ni * 16 + r16;
                        int ch4 = colh >> 2, cl = colh & 3;
                        #pragma unroll
                        for (int rr = 0; rr < 4; rr++) {
                            int r = rw + mi * 16 + q * 4 + rr;
                            cf[r * 64 + (((ch4 ^ (r & 15)) << 2) | cl)] = acc[mi][ni][rr];
                        }
                    }
                }
            }
            __syncthreads();
            if (mode == 2) {                           // residual RMW into tokf
                #pragma unroll
                for (int it = 0; it < 8; ++it) {
                    int idx = tid + it * 256;          // (r:7 | c4:4)
                    int r = idx >> 4, c4 = idx & 15;
                    f32x4 v = *(const f32x4*)&cf[r * 64 + ((c4 ^ (r & 15)) << 2)];
                    int col = hp * 64 + c4 * 4;
                    float* tp = tokf + (size_t)(m0 + r) * 128 + col;
                    f32x4 t = *(const f32x4*)tp;
                    #pragma unroll
                    for (int e = 0; e < 4; e++) t[e] += v[e] + b2f(bias[col + e]);
                    *(f32x4*)tp = t;
                }
            } else {                                   // v1f fp32: [bh][i=it][l=jt][32]
                #pragma unroll
                for (int it = 0; it < 8; ++it) {
                    int idx = tid + it * 256;          // (hh:1 | itl:1 | jt:6 | d4:3)
                    int hh = idx >> 10, itl = (idx >> 9) & 1, jt = (idx >> 3) & 63, d4 = idx & 7;
                    int r = itl * 64 + jt;
                    int colh = hh * 32 + d4 * 4;
                    f32x4 v = *(const f32x4*)&cf[r * 64 + (((colh >> 2) ^ (r & 15)) << 2)];
                    int h = hp * 2 + hh;
                    *(f32x4*)&tokf[((((size_t)(bl * 4 + h)) * 64 + it0 + itl) * 64 + jt) * 32 + d4 * 4] = v;
                }
            }
        }
    }
}

// ---------------------------------------------------------------- s = QK^T/scale (bf16 out)
__global__ __launch_bounds__(64) void attn_s_kernel(
    const u16* __restrict__ qb, const u16* __restrict__ kb, u16* __restrict__ s)
{
    __shared__ __align__(16) u16 qs[64 * 40];
    __shared__ __align__(16) u16 ks_[64 * 40];
    int g = blockIdx.x;
    int l = g & 63, bh = g >> 6;
    const u16* Q = qb + ((size_t)bh * 64 + l) * 2048;
    const u16* Kp = kb + ((size_t)bh * 64 + l) * 2048;
    int lane = threadIdx.x;
    #pragma unroll
    for (int it = 0; it < 4; ++it) {
        int idx = lane + it * 64;
        int row = idx >> 2, c4 = idx & 3;
        *(uint4*)&qs[row * 40 + c4 * 8] = *(const uint4*)(Q + row * 32 + c4 * 8);
        *(uint4*)&ks_[row * 40 + c4 * 8] = *(const uint4*)(Kp + row * 32 + c4 * 8);
    }
    __syncthreads();
    int q = lane >> 4, r16 = lane & 15;
    f32x4 acc[4][4];
    #pragma unroll
    for (int mi = 0; mi < 4; mi++)
        #pragma unroll
        for (int ni = 0; ni < 4; ni++) acc[mi][ni] = (f32x4){0.f, 0.f, 0.f, 0.f};
    bf16x8 fa[4], fb[4];
    #pragma unroll
    for (int mi = 0; mi < 4; mi++) fa[mi] = *(const bf16x8*)&qs[(mi * 16 + r16) * 40 + q * 8];
    #pragma unroll
    for (int ni = 0; ni < 4; ni++) fb[ni] = *(const bf16x8*)&ks_[(ni * 16 + r16) * 40 + q * 8];
    #pragma unroll
    for (int mi = 0; mi < 4; mi++)
        #pragma unroll
        for (int ni = 0; ni < 4; ni++)
            acc[mi][ni] = __builtin_amdgcn_mfma_f32_16x16x32_bf16(fa[mi], fb[ni], acc[mi][ni], 0, 0, 0);
    u16* sb = s + (size_t)bh * 262144 + l * 64;
    #pragma unroll
    for (int mi = 0; mi < 4; mi++)
        #pragma unroll
        for (int ni = 0; ni < 4; ni++)
            #pragma unroll
            for (int rr = 0; rr < 4; rr++) {
                int i = mi * 16 + q * 4 + rr, j = ni * 16 + r16;
                sb[(size_t)i * 4096 + j] = f2b(acc[mi][ni][rr] * INV_SCALE);
            }
}

// ---------------------------------------------------------------- softmax over l (bf16 in/out)
__global__ __launch_bounds__(256) void softmax_kernel(u16* __restrict__ s) {
    int g = blockIdx.x * 256 + threadIdx.x;
    int j = g & 63, bhi = g >> 6;
    u16* p = s + (size_t)bhi * 4096 + j;
    float r[64];
    float mx = -1e30f;
    #pragma unroll
    for (int l = 0; l < 64; l++) { r[l] = b2f(p[l * 64]); mx = fmaxf(mx, r[l]); }
    float sum = 0.f;
    #pragma unroll
    for (int l = 0; l < 64; l++) { r[l] = __expf(r[l] - mx); sum += r[l]; }
    float is = 1.0f / sum;
    #pragma unroll
    for (int l = 0; l < 64; l++) p[l * 64] = f2b(r[l] * is);
}

// ---------------------------------------------------------------- o = sum_l a*v1*v2
// block = (bh, 8-i-group), 512 threads (8 waves: 4 d-chunks x 2 i-halves).
// All operands staged in LDS per 4-l chunk; global loads register-prefetched so
// they overlap the previous chunk's compute. Inner loop: pure LDS + VALU.
__global__ __launch_bounds__(512) void attn_o_kernel(
    const u16* __restrict__ a, const float* __restrict__ v1f, const u16* __restrict__ v2b,
    u16* __restrict__ ob)
{
    __shared__ __align__(16) float v2s[4 * 2304];     // 36864 B, stride 36 (conflict-free, R6 PMC)
    __shared__ __align__(16) u16   as_[8 * 4 * 64];   // 4 KB
    __shared__ __align__(16) float v1s[8 * 4 * 32];   // 4 KB
    int bh = blockIdx.x;
    int i0 = blockIdx.y * 8;
    int bl = bh >> 2, h = bh & 3;
    int tid = threadIdx.x;
    int w = __builtin_amdgcn_readfirstlane(tid >> 6);  // 0..7
    int j = tid & 63;
    int ih = w & 1;                                    // i-half
    int dh = (w >> 1) * 8;                             // d-chunk base
    const u16*   v2base = v2b + (size_t)bh * 131072;
    const float* v1base = v1f + (size_t)bh * 131072 + (size_t)i0 * 2048;
    const u16*   abase  = a + (size_t)bh * 262144 + (size_t)i0 * 4096;

    // prefetch registers
    uint4 pv2[2]; unsigned pa[2]; float pv1[2];
    int ia[2], la[2], ja[2], iv[2], lv[2], dv[2], lz[2], jz[2], cz[2];
    #pragma unroll
    for (int it = 0; it < 2; ++it) {
        int idx = tid + it * 512;            // [0,1024)
        lz[it] = idx >> 8; jz[it] = (idx >> 2) & 63; cz[it] = idx & 3;   // v2
        ia[it] = idx >> 7; la[it] = (idx >> 5) & 3; ja[it] = idx & 31;   // a
        iv[it] = idx >> 7; lv[it] = (idx >> 5) & 3; dv[it] = idx & 31;   // v1
    }

#define LOAD_CHUNK(l0_)                                                             \
    _Pragma("unroll")                                                               \
    for (int it = 0; it < 2; ++it) {                                                \
        pv2[it] = *(const uint4*)(v2base + ((size_t)((l0_) + lz[it]) * 64 + jz[it]) * 32 + cz[it] * 8); \
        pa[it]  = *(const unsigned*)(abase + (size_t)ia[it] * 4096 + ((l0_) + la[it]) * 64 + ja[it] * 2); \
        pv1[it] = v1base[(size_t)iv[it] * 2048 + ((l0_) + lv[it]) * 32 + dv[it]];   \
    }

#define STORE_CHUNK()                                                               \
    _Pragma("unroll")                                                               \
    for (int it = 0; it < 2; ++it) {                                                \
        const u16* ds = (const u16*)&pv2[it];                                       \
        float* dst = &v2s[lz[it] * 2304 + jz[it] * 36 + cz[it] * 8];                \
        _Pragma("unroll")                                                           \
        for (int e = 0; e < 8; e++) dst[e] = b2f(ds[e]);                            \
        *(unsigned*)&as_[ia[it] * 256 + la[it] * 64 + ja[it] * 2] = pa[it];         \
        v1s[iv[it] * 128 + lv[it] * 32 + dv[it]] = pv1[it];                         \
    }

    float acc[4][8];
    #pragma unroll
    for (int i = 0; i < 4; i++)
        #pragma unroll
        for (int e = 0; e < 8; e++) acc[i][e] = 0.f;

    LOAD_CHUNK(0);
    for (int ch = 0; ch < 16; ++ch) {
        if (ch) __syncthreads();             // previous chunk's readers done
        STORE_CHUNK();
        if (ch + 1 < 16) LOAD_CHUNK((ch + 1) * 4);
        __syncthreads();
        #pragma unroll
        for (int lc = 0; lc < 4; ++lc) {
            const float* vp = &v2s[lc * 2304 + j * 36 + dh];
            float v2r[8];
            *(f32x4*)&v2r[0] = *(const f32x4*)vp;
            *(f32x4*)&v2r[4] = *(const f32x4*)(vp + 4);
            #pragma unroll
            for (int ii = 0; ii < 4; ++ii) {
                int iL = ih * 4 + ii;
                float av = b2f(as_[iL * 256 + lc * 64 + j]);
                const float* v1p = &v1s[iL * 128 + lc * 32 + dh];   // broadcast reads
                #pragma unroll
                for (int e = 0; e < 8; e++)
                    acc[ii][e] += (av * v1p[e]) * v2r[e];
            }
        }
    }
#undef LOAD_CHUNK
#undef STORE_CHUNK

    #pragma unroll
    for (int ii = 0; ii < 4; ++ii) {
        int iL = ih * 4 + ii;
        u16 tmp[8];
        #pragma unroll
        for (int e = 0; e < 8; e++) tmp[e] = f2b(acc[ii][e]);
        *(uint4*)(ob + ((size_t)(bl * 64 + i0 + iL) * 64 + j) * 128 + h * 32 + dh) = *(uint4*)tmp;
    }
}

// ---------------------------------------------------------------- LayerNorm
__global__ __launch_bounds__(256) void ln_kernel(
    float* __restrict__ tokf, u16* __restrict__ tokb,
    const u16* __restrict__ g, const u16* __restrict__ bp)
{
    int row = blockIdx.x * 4 + (threadIdx.x >> 6);
    int lane = threadIdx.x & 63;
    float* p = tokf + (size_t)row * 128 + lane * 2;
    float x0 = p[0], x1 = p[1];
    float s = x0 + x1, sq = x0 * x0 + x1 * x1;
    #pragma unroll
    for (int off = 32; off; off >>= 1) { s += __shfl_xor(s, off, 64); sq += __shfl_xor(sq, off, 64); }
    float mean = s * (1.0f / 128.0f);
    float var = sq * (1.0f / 128.0f) - mean * mean;
    float rs = rsqrtf(var + 1e-5f);
    float y0 = (x0 - mean) * rs * b2f(g[lane * 2]) + b2f(bp[lane * 2]);
    float y1 = (x1 - mean) * rs * b2f(g[lane * 2 + 1]) + b2f(bp[lane * 2 + 1]);
    p[0] = y0; p[1] = y1;
    unsigned int pk = (unsigned int)f2b(y0) | ((unsigned int)f2b(y1) << 16);
    *(unsigned int*)(tokb + (size_t)row * 128 + lane * 2) = pk;
}

// ---------------------------------------------------------------- final diag head (fp32 out)
__global__ __launch_bounds__(256) void out_kernel(
    const float* __restrict__ tokf, const u16* __restrict__ Wout, const u16* __restrict__ bout,
    float* __restrict__ out)
{
    int g = blockIdx.x * 256 + threadIdx.x;   // [0,512)
    int b = g >> 6, i = g & 63;
    const float* p = tokf + ((size_t)(b * 64 + i) * 64 + i) * 128;
    float s = b2f(bout[0]);
    #pragma unroll
    for (int d = 0; d < 128; d++) s += p[d] * b2f(Wout[d]);
    out[g] = s;
}

// ---------------------------------------------------------------- launch
extern "C" void kernel_launch(void* const* d_in, const int* in_sizes, int n_in,
                              void* d_out, int out_size, void* d_ws, size_t ws_size,
                              hipStream_t stream) {
    const void* mask = d_in[2];
    ParamPtrs pp;
    for (int k = 0; k < NSEG; ++k) pp.p[k] = d_in[k < 2 ? k : k + 1];   // skip mask

    char* ws = (char*)d_ws;
    u16* arena = (u16*)ws;
    #define AP(k) ((const u16*)ws + h_seg_off[k])
    int*   mmode = (int*)(ws + 1835008);
    float* tokf  = (float*)(ws + 2097152);      // 16 MB
    u16*   tokb  = (u16*)(ws + 18874368);       //  8 MB
    const size_t base = 27262976;
    const size_t MB = 1048576ULL;

    // adaptive splits vs ws_size: attn needs base + 7*NB MB
    int NB = 8;
    while (NB > 1 && base + (size_t)NB * 7 * MB > ws_size) NB >>= 1;
    int F = 1;
    while (F < 8 && base + (size_t)(32768 / F) * 1024ULL > ws_size) F <<= 1;

    u16*   qb  = (u16*)(ws + base);                       // NB MB
    u16*   kb  = (u16*)(ws + base + (size_t)NB * MB);     // NB MB
    u16*   v2b = (u16*)(ws + base + (size_t)NB * 2 * MB); // NB MB
    float* v1f = (float*)(ws + base + (size_t)NB * 3 * MB); // 2*NB MB
    u16*   sb  = (u16*)(ws + base + (size_t)NB * 5 * MB);   // 2*NB MB
    u16*   ob  = qb;                              // q dead after attn_s
    u16*   ffb = qb;                              // attention bufs dead in FF phase

    convert_params<<<1024, 256, 0, stream>>>(pp, arena);
    probe_kernel<<<1, 256, 0, stream>>>(mask, mmode);
    assemble_kernel<<<4096, 256, 0, stream>>>(AP(0), AP(1), mask, mmode,
                                              AP(2), AP(3), AP(4), AP(5), AP(6), tokf, tokb);

    for (int l = 0; l < 3; ++l) {
        const u16* Wq_l  = AP(7)  + l * 16384;
        const u16* Wk_l  = AP(8)  + l * 16384;
        const u16* Wv1_l = AP(9)  + l * 16384;
        const u16* Wv2_l = AP(10) + l * 16384;
        const u16* Wo_l  = AP(11) + l * 16384;
        const u16* bo_l  = AP(12) + l * 128;
        const u16* g1_l  = AP(13) + l * 128;
        const u16* be1_l = AP(14) + l * 128;
        const u16* W1_l  = AP(15) + l * 65536;
        const u16* b1_l  = AP(16) + l * 512;
        const u16* W2_l  = AP(17) + l * 65536;
        const u16* b2_l  = AP(18) + l * 128;
        const u16* g2_l  = AP(19) + l * 128;
        const u16* be2_l = AP(20) + l * 128;

        for (int r = 0; r < 8 / NB; ++r) {
            size_t rowOff = (size_t)r * NB * 4096;
            gemm_kernel<<<dim3(NB * 32, 4), 256, 0, stream>>>(
                tokb + rowOff * 128, 128, Wq_l, Wk_l, Wv1_l, Wv2_l,
                128, (const u16*)0, 128, 3, (u16*)0, 0, v1f, qb, kb, v2b);
            attn_s_kernel<<<NB * 256, 64, 0, stream>>>(qb, kb, sb);
            softmax_kernel<<<NB * 64, 256, 0, stream>>>(sb);
            attn_o_kernel<<<dim3(NB * 4, 8), 512, 0, stream>>>(sb, v1f, v2b, ob);
            gemm_kernel<<<dim3(NB * 32, 1), 256, 0, stream>>>(
                ob, 128, Wo_l, (const u16*)0, (const u16*)0, (const u16*)0,
                128, bo_l, 128, 2, (u16*)0, 0, tokf + rowOff * 128,
                (u16*)0, (u16*)0, (u16*)0);
        }
        ln_kernel<<<8192, 256, 0, stream>>>(tokf, tokb, g1_l, be1_l);
        for (int f = 0; f < F; ++f) {
            size_t r0 = (size_t)f * (32768 / F);
            int RB = (32768 / F) / 128;
            gemm_kernel<<<dim3(RB, 4), 256, 0, stream>>>(
                tokb + r0 * 128, 128, W1_l, (const u16*)0, (const u16*)0, (const u16*)0,
                512, b1_l, 128, 1, ffb, 512, (float*)0, (u16*)0, (u16*)0, (u16*)0);
            gemm_kernel<<<dim3(RB, 1), 256, 0, stream>>>(
                ffb, 512, W2_l, (const u16*)0, (const u16*)0, (const u16*)0,
                128, b2_l, 512, 2, (u16*)0, 0, tokf + r0 * 128,
                (u16*)0, (u16*)0, (u16*)0);
        }
        ln_kernel<<<8192, 256, 0, stream>>>(tokf, tokb, g2_l, be2_l);
    }
    out_kernel<<<2, 256, 0, stream>>>(tokf, AP(21), AP(22), (float*)d_out);
}